// Round 2
// baseline (5696.617 us; speedup 1.0000x reference)
//
#include <hip/hip_runtime.h>
#include <math.h>

#define NN 32768
#define HH 128
#define DD 16
#define BB 256
#define E2N (NN*DD)
#define NF (NN*HH)

__device__ __forceinline__ float fsig(float x) { return 1.0f/(1.0f + __expf(-x)); }
__device__ __forceinline__ float ftanh(float x) {
  float cx = fminf(fmaxf(x, -15.0f), 15.0f);
  float e = __expf(2.0f*cx);
  return 1.0f - 2.0f/(e + 1.0f);
}

__device__ __forceinline__ void gload_lds16(const float* g, float* l) {
  __builtin_amdgcn_global_load_lds((const __attribute__((address_space(1))) void*)g,
                                   (__attribute__((address_space(3))) void*)l, 16, 0, 0);
}

// ---------------- transpose prep (all weights -> [K][Nout] layout) ----------------
struct TDesc { const float* src; float* dst; int R; int C; };
struct TDescArr { TDesc d[26]; };

__global__ void transpose_many(TDescArr da) {
  TDesc t = da.d[blockIdx.y];
  int idx = blockIdx.x*256 + threadIdx.x;
  if (idx < t.R*t.C) {
    int r = idx / t.C, c = idx - r*t.C;
    t.dst[(size_t)c*t.R + r] = t.src[idx];
  }
}

__global__ void bias_sum_kernel(const float* __restrict__ bih, const float* __restrict__ bhh,
                                float* __restrict__ bsum) {
  int i = blockIdx.x*256 + threadIdx.x;
  if (i < 2048) bsum[i] = bih[i] + bhh[i];
}

// ---------------- embeddings ----------------
__global__ void embed3_kernel(const int* __restrict__ a_ids, const int* __restrict__ d_ids,
                              const int* __restrict__ a2_ids,
                              const float* __restrict__ ea, const float* __restrict__ ed,
                              const float* __restrict__ ea2,
                              float* __restrict__ ha, float* __restrict__ hd,
                              float* __restrict__ hg2) {
  int idx = blockIdx.x*256 + threadIdx.x;
  int n = idx >> 7, j = idx & 127;
  int w = blockIdx.y;
  if (w == 0)      ha[idx]  = ea[(size_t)a_ids[n]*128 + j];
  else if (w == 1) hd[idx]  = ed[(size_t)d_ids[n]*128 + j];
  else             hg2[idx] = ea2[(size_t)a2_ids[n]*128 + j];
}

// ---------------- generic GEMM: C = act(A @ W^T + bias + beta*C) ----------------
template<int BN, int ACT>
__global__ __launch_bounds__(256) void gemm_nt(
    const float* __restrict__ A0, const float* __restrict__ A1,
    const float* __restrict__ A2, const float* __restrict__ A3,
    int lda, const float* __restrict__ WT, const float* __restrict__ bias,
    float* __restrict__ C, int K, int beta)
{
  extern __shared__ float sm[];
  const int KP = K + 4;
  float* At = sm;             // [32][KP]
  float* Bc = sm + 32*KP;     // [16][BN]
  const int tid = threadIdx.x;
  const int m0 = blockIdx.x*32;
  const int ng = tid >> 5, cg = tid & 31;
  const int n0 = ng*4, c4 = cg*4;
  constexpr int G = BN/128;
  float acc[G][4][4];
#pragma unroll
  for (int g=0; g<G; ++g)
#pragma unroll
    for (int i=0;i<4;++i)
#pragma unroll
      for (int e=0;e<4;++e) acc[g][i][e] = 0.0f;

  const int nf4 = K >> 2;
  for (int idx = tid; idx < 32*nf4; idx += 256) {
    int row = idx / nf4;
    int kk = (idx - row*nf4) << 2;
    const float* Ap = (kk < 128) ? A0 : (kk < 256) ? A1 : (kk < 384) ? A2 : A3;
    float4 v = *(const float4*)(Ap + (size_t)(m0+row)*lda + (kk & 127));
    *(float4*)(At + row*KP + kk) = v;
  }
  const int nchunk = K >> 4;
  for (int kc = 0; kc < nchunk; ++kc) {
    __syncthreads();
    for (int idx = tid; idx < 16*(BN/4); idx += 256) {
      int kk = idx / (BN/4);
      int jq = idx - kk*(BN/4);
      *(float4*)(Bc + kk*BN + jq*4) = *(const float4*)(WT + (size_t)(kc*16+kk)*BN + jq*4);
    }
    __syncthreads();
    for (int k=0;k<16;++k) {
      const int kk = kc*16 + k;
      float av[4];
#pragma unroll
      for (int i=0;i<4;++i) av[i] = At[(n0+i)*KP + kk];
#pragma unroll
      for (int g=0; g<G; ++g) {
        float4 bv = *(const float4*)(Bc + k*BN + g*128 + c4);
        float bb[4] = {bv.x, bv.y, bv.z, bv.w};
#pragma unroll
        for (int i=0;i<4;++i)
#pragma unroll
          for (int e=0;e<4;++e)
            acc[g][i][e] += av[i]*bb[e];
      }
    }
  }
#pragma unroll
  for (int g=0; g<G; ++g) {
#pragma unroll
    for (int i=0;i<4;++i) {
      float* dst = C + (size_t)(m0+n0+i)*BN + g*128 + c4;
      float o[4];
#pragma unroll
      for (int e=0;e<4;++e) o[e] = acc[g][i][e];
      if (bias) {
#pragma unroll
        for (int e=0;e<4;++e) o[e] += bias[g*128 + c4 + e];
      }
      if (beta) {
        float4 p = *(const float4*)dst;
        o[0]+=p.x; o[1]+=p.y; o[2]+=p.z; o[3]+=p.w;
      }
      if (ACT==1) {
#pragma unroll
        for (int e=0;e<4;++e) o[e] = fmaxf(o[e], 0.0f);
      }
      *(float4*)dst = make_float4(o[0],o[1],o[2],o[3]);
    }
  }
}

// ---------------- persistent LSTM aggregator v2 ----------------
// 32 rows/block, 4 blocks/CU (LDS 33.3KB), double-buffered Whh chunks of 4 k,
// staged via global_load_lds (prefetch chunk kc+1 during compute of kc).
__global__ __launch_bounds__(256, 4) void lstm_kernel(
    float* __restrict__ hL, const float* __restrict__ Gx,
    const int* __restrict__ nbrA, const int* __restrict__ nbrD,
    const float* __restrict__ WT0, const float* __restrict__ WT1)
{
  __shared__ float h_tile[32*132];      // 16896 B
  __shared__ float Bc[2*4*512];         // 16384 B (double-buffered [4][512])
  const int tid = threadIdx.x;
  const int r0 = blockIdx.x*32;
  const bool dir = (r0 >= NN);
  const int* nbr = dir ? nbrD : nbrA;
  const int nb = dir ? (r0 - NN) : r0;
  const float* gxb = Gx + (dir ? (size_t)NN*512 : (size_t)0);
  const float* WT = dir ? WT1 : WT0;
  const int ng = tid >> 5, cg = tid & 31;
  const int n0 = ng*4, c4 = cg*4;
  float cst[4][4];
  float hv[4][4];
#pragma unroll
  for (int i=0;i<4;++i)
#pragma unroll
    for (int e=0;e<4;++e) cst[i][e] = 0.0f;

  // prologue: stage chunk 0 (for t=1) into buf0
  {
    const float* g0 = WT + tid*4;
    float* l0 = (float*)Bc + tid*4;
    gload_lds16(g0, l0);
    gload_lds16(g0 + 1024, l0 + 1024);
  }

  for (int t=0; t<16; ++t) {
    float acc[4][4][4];   // [gate][node][elem]
    // gather precomputed input-gate pre-activations (serves as acc init)
#pragma unroll
    for (int i=0;i<4;++i) {
      const int gr = nbr[(size_t)(nb + n0 + i)*DD + t];
      const float* row = gxb + (size_t)gr*512;
#pragma unroll
      for (int g=0; g<4; ++g) {
        float4 v = *(const float4*)(row + g*128 + c4);
        acc[g][i][0]=v.x; acc[g][i][1]=v.y; acc[g][i][2]=v.z; acc[g][i][3]=v.w;
      }
    }
    if (t > 0) {
      for (int kc=0; kc<32; ++kc) {
        __syncthreads();   // buf[kc&1] staged; prior chunk's reads drained
        if (kc < 31) {     // prefetch chunk kc+1 into buf^1 (overlaps compute)
          const float* gsrc = WT + (kc+1)*2048 + tid*4;
          float* ldst = (float*)Bc + ((kc+1)&1)*2048 + tid*4;
          gload_lds16(gsrc, ldst);
          gload_lds16(gsrc + 1024, ldst + 1024);
        }
        const float* Bp = Bc + (kc&1)*2048;
        float4 av4[4];
#pragma unroll
        for (int i=0;i<4;++i)
          av4[i] = *(const float4*)(h_tile + (n0+i)*132 + kc*4);
#pragma unroll
        for (int k=0;k<4;++k) {
          float avk[4];
#pragma unroll
          for (int i=0;i<4;++i)
            avk[i] = (k==0) ? av4[i].x : (k==1) ? av4[i].y : (k==2) ? av4[i].z : av4[i].w;
#pragma unroll
          for (int g=0;g<4;++g) {
            float4 bv = *(const float4*)(Bp + k*512 + g*128 + c4);
            float bb[4] = {bv.x,bv.y,bv.z,bv.w};
#pragma unroll
            for (int i=0;i<4;++i)
#pragma unroll
              for (int e=0;e<4;++e)
                acc[g][i][e] += avk[i]*bb[e];
          }
        }
      }
    }
    __syncthreads();   // all h_tile reads for this step done
#pragma unroll
    for (int i=0;i<4;++i) {
#pragma unroll
      for (int e=0;e<4;++e) {
        float ig = fsig(acc[0][i][e]);
        float fg = fsig(acc[1][i][e]);
        float gg = ftanh(acc[2][i][e]);
        float og = fsig(acc[3][i][e]);
        float cc = fg*cst[i][e] + ig*gg;
        cst[i][e] = cc;
        hv[i][e] = og*ftanh(cc);
      }
      *(float4*)(h_tile + (n0+i)*132 + c4) = make_float4(hv[i][0],hv[i][1],hv[i][2],hv[i][3]);
    }
    if (t > 0 && t < 15) {   // re-stage chunk 0 for next step into buf0
      const float* g0 = WT + tid*4;
      float* l0 = (float*)Bc + tid*4;
      gload_lds16(g0, l0);
      gload_lds16(g0 + 1024, l0 + 1024);
    }
    __syncthreads();   // h_tile writes + chunk-0 staging visible
  }
#pragma unroll
  for (int i=0;i<4;++i)
    *(float4*)(hL + (size_t)(r0+n0+i)*HH + c4) = make_float4(hv[i][0],hv[i][1],hv[i][2],hv[i][3]);
}

// ---------------- GGC scatter-add: a[dst] += m[src] (128 floats/edge) ----------------
__global__ void scatter_add_kernel(float* __restrict__ a, const float* __restrict__ m,
                                   const int* __restrict__ src, const int* __restrict__ dst) {
  int wid = (blockIdx.x*256 + threadIdx.x) >> 6;
  int lane = threadIdx.x & 63;
  int s = src[wid], d = dst[wid];
  const float* mr = m + (size_t)s*128;
  float* ar = a + (size_t)d*128;
  atomicAdd(ar + lane, mr[lane]);
  atomicAdd(ar + 64 + lane, mr[64 + lane]);
}

// ---------------- GRU pointwise ----------------
__global__ void gru_update_kernel(float* __restrict__ hh, const float* __restrict__ gi,
                                  const float* __restrict__ gh) {
  int idx = blockIdx.x*256 + threadIdx.x;
  int n = idx >> 7, j = idx & 127;
  const float* gin = gi + (size_t)n*384;
  const float* ghn = gh + (size_t)n*384;
  float r  = fsig(gin[j] + ghn[j]);
  float z  = fsig(gin[128+j] + ghn[128+j]);
  float nn2 = ftanh(gin[256+j] + r*ghn[256+j]);
  float h = hh[idx];
  hh[idx] = (1.0f - z)*nn2 + z*h;
}

// ---------------- LayerNorm (+optional residual add) + leaky relu ----------------
__global__ void ln_lrelu_kernel(float* __restrict__ out, const float* __restrict__ x,
                                const float* __restrict__ add,
                                const float* __restrict__ g, const float* __restrict__ b) {
  int n = blockIdx.x, j = threadIdx.x;   // 128 threads
  size_t base = (size_t)n*128;
  float v = x[base+j];
  if (add) v += add[base+j];
  __shared__ float sh[4];
  float s = v;
#pragma unroll
  for (int m=32; m>=1; m>>=1) s += __shfl_xor(s, m, 64);
  if ((j&63)==0) sh[j>>6] = s;
  __syncthreads();
  float mean = (sh[0]+sh[1]) * 0.0078125f;
  float d = v - mean;
  float q = d*d;
#pragma unroll
  for (int m=32; m>=1; m>>=1) q += __shfl_xor(q, m, 64);
  if ((j&63)==0) sh[2+(j>>6)] = q;
  __syncthreads();
  float var = (sh[2]+sh[3]) * 0.0078125f;
  float y = d * rsqrtf(var + 1e-5f) * g[j] + b[j];
  out[base+j] = (y >= 0.0f) ? y : 0.01f*y;
}

// ---------------- segment mean (contiguous 128-node segments) ----------------
__global__ void segmean_kernel(float* __restrict__ out, const float* __restrict__ x,
                               const float* __restrict__ y) {
  int b = blockIdx.x, j = threadIdx.x;   // 128 threads, 256 blocks
  float s = 0.0f;
  for (int r=0; r<128; ++r) {
    size_t n = (size_t)(b*128 + r)*128 + j;
    s += x[n];
    if (y) s += y[n];
  }
  out[(size_t)b*128 + j] = s * 0.0078125f;
}

// ---------------- classifier head ----------------
__global__ void cls_kernel(float* __restrict__ out, const float* __restrict__ h2,
                           const float* __restrict__ Wc, const float* __restrict__ bc) {
  int gid = blockIdx.x*256 + threadIdx.x;
  if (gid >= BB*10) return;
  int mrow = gid/10, c = gid - mrow*10;
  const float* arow = h2 + (size_t)mrow*128;
  const float* wrow = Wc + (size_t)c*128;
  float s = bc[c];
  for (int k=0;k<128;++k) s += arow[k]*wrow[k];
  out[gid] = s;
}

__global__ void bail_kernel(float* out, float v) {
  if (threadIdx.x==0 && blockIdx.x==0) out[0] = v;
}

// ---------------- host orchestration ----------------
extern "C" void kernel_launch(void* const* d_in, const int* in_sizes, int n_in,
                              void* d_out, int out_size, void* d_ws, size_t ws_size,
                              hipStream_t stream)
{
  const int* act_ids  = (const int*)d_in[0];
  const int* dur_ids  = (const int*)d_in[1];
  const int* act2_ids = (const int*)d_in[2];
  const int* nbr_a2d  = (const int*)d_in[3];
  const int* nbr_d2a  = (const int*)d_in[4];
  const int* src2     = (const int*)d_in[5];
  const int* dst2     = (const int*)d_in[6];
  const float* emb_act     = (const float*)d_in[8];
  const float* emb_dur     = (const float*)d_in[9];
  const float* emb_act2    = (const float*)d_in[10];
  const float* transform_W = (const float*)d_in[11];
  const float* transform_b = (const float*)d_in[12];
  const float* ggc_W   = (const float*)d_in[13];
  const float* ggc_b   = (const float*)d_in[14];
  const float* gru_Wih = (const float*)d_in[15];
  const float* gru_Whh = (const float*)d_in[16];
  const float* gru_bih = (const float*)d_in[17];
  const float* gru_bhh = (const float*)d_in[18];
  const float* hn_g    = (const float*)d_in[19];
  const float* hn_b    = (const float*)d_in[20];
  const float* lstm_Wih = (const float*)d_in[21];
  const float* lstm_Whh = (const float*)d_in[22];
  const float* lstm_bih = (const float*)d_in[23];
  const float* lstm_bhh = (const float*)d_in[24];
  const float* fcs_W = (const float*)d_in[25];
  const float* fcs_b = (const float*)d_in[26];
  const float* fcn_W = (const float*)d_in[27];
  const float* fcn_b = (const float*)d_in[28];
  const float* n1_g = (const float*)d_in[29];
  const float* n1_b = (const float*)d_in[30];
  const float* n3_g = (const float*)d_in[31];
  const float* n3_b = (const float*)d_in[32];
  const float* mh_W1 = (const float*)d_in[33];
  const float* mh_b1 = (const float*)d_in[34];
  const float* mh_W2 = (const float*)d_in[35];
  const float* mh_b2 = (const float*)d_in[36];
  const float* mo_W1 = (const float*)d_in[37];
  const float* mo_b1 = (const float*)d_in[38];
  const float* mo_W2 = (const float*)d_in[39];
  const float* mo_b2 = (const float*)d_in[40];
  const float* mlp_W1 = (const float*)d_in[41];
  const float* mlp_b1 = (const float*)d_in[42];
  const float* mlp_W2 = (const float*)d_in[43];
  const float* mlp_b2 = (const float*)d_in[44];
  const float* cls_W = (const float*)d_in[45];
  const float* cls_b = (const float*)d_in[46];

  float* ws = (float*)d_ws;
  float* ha   = ws;
  float* hd   = ws + (size_t)NF;
  float* hg2  = ws + 2*(size_t)NF;
  float* res  = ws + 3*(size_t)NF;
  float* hh   = ws + 4*(size_t)NF;
  float* SCR  = ws + 5*(size_t)NF;
  float* mb   = SCR;
  float* abuf = SCR + (size_t)NF;
  float* gi   = SCR + 2*(size_t)NF;
  float* gh   = SCR + 5*(size_t)NF;
  float* hnf  = mb;
  float* Gx   = SCR;
  float* hLb  = SCR + 8*(size_t)NF;
  float* SMALL = ws + 15*(size_t)NF;
  float* hg2m = SMALL;
  float* hgm  = SMALL + 32768;
  float* o1b  = SMALL + 65536;
  float* o2b  = SMALL + 98304;
  float* t1b  = SMALL + 131072;
  float* t2b  = SMALL + 163840;
  float* h1b  = SMALL + 196608;
  float* h2b  = SMALL + 262144;
  float* bsum = SMALL + 294912;
  float* WTb  = SMALL + 296960;
  const size_t NEED_BYTES = (size_t)(15*(size_t)NF + 296960 + 1032192) * 4;
  if (ws_size < NEED_BYTES) {
    hipMemsetAsync(d_out, 0, (size_t)out_size*sizeof(float), stream);
    bail_kernel<<<1,64,0,stream>>>((float*)d_out, (float)ws_size);
    return;
  }
  float* na = hg2;
  float* nd = res;

  const int O_TRANSFORM = 0;
  const int O_GGC      = 32768;
  const int O_GRUWIH   = 49152;
  const int O_GRUWHH   = 98304;
  const int O_LSTMWIH  = 147456;
  const int O_LSTMWHH  = 409600;
  const int O_FCS      = 671744;
  const int O_FCN      = 737280;
  const int O_MH1      = 802816;
  const int O_MH2      = 819200;
  const int O_MO1      = 835584;
  const int O_MO2      = 851968;
  const int O_MLP1     = 868352;
  const int O_MLP2     = 999424;

  TDescArr da;
  int di = 0;
  auto addT = [&](const float* s, float* d, int R, int C){ da.d[di].src=s; da.d[di].dst=d; da.d[di].R=R; da.d[di].C=C; ++di; };
  addT(transform_W, WTb + O_TRANSFORM, 128, 256);
  addT(ggc_W,   WTb + O_GGC,    128, 128);
  addT(gru_Wih, WTb + O_GRUWIH, 384, 128);
  addT(gru_Whh, WTb + O_GRUWHH, 384, 128);
  for (int i=0;i<4;++i) addT(lstm_Wih + (size_t)i*65536, WTb + O_LSTMWIH + i*65536, 512, 128);
  for (int i=0;i<4;++i) addT(lstm_Whh + (size_t)i*65536, WTb + O_LSTMWHH + i*65536, 512, 128);
  for (int i=0;i<4;++i) addT(fcs_W + (size_t)i*16384, WTb + O_FCS + i*16384, 128, 128);
  for (int i=0;i<4;++i) addT(fcn_W + (size_t)i*16384, WTb + O_FCN + i*16384, 128, 128);
  addT(mh_W1, WTb + O_MH1, 128, 128);
  addT(mh_W2, WTb + O_MH2, 128, 128);
  addT(mo_W1, WTb + O_MO1, 128, 128);
  addT(mo_W2, WTb + O_MO2, 128, 128);
  addT(mlp_W1, WTb + O_MLP1, 256, 512);
  addT(mlp_W2, WTb + O_MLP2, 128, 256);
  transpose_many<<<dim3(512, 26), 256, 0, stream>>>(da);
  bias_sum_kernel<<<8, 256, 0, stream>>>(lstm_bih, lstm_bhh, bsum);

  auto smemK = [](int K, int BN){ return (size_t)(32*(K+4) + 16*BN)*4; };
  const int gN = NN/32;
  const int gB = BB/32;

  embed3_kernel<<<dim3(NF/256, 3), 256, 0, stream>>>(act_ids, dur_ids, act2_ids,
      emb_act, emb_dur, emb_act2, ha, hd, hg2);
  gemm_nt<128,0><<<gN, 256, smemK(256,128), stream>>>(hg2, hd, nullptr, nullptr, 128,
      WTb + O_TRANSFORM, transform_b, res, 256, 0);
  hipMemcpyAsync(hh, res, (size_t)NF*4, hipMemcpyDeviceToDevice, stream);

  for (int it=0; it<2; ++it) {
    gemm_nt<128,0><<<gN, 256, smemK(128,128), stream>>>(hh, nullptr, nullptr, nullptr, 128,
        WTb + O_GGC, ggc_b, mb, 128, 0);
    hipMemsetAsync(abuf, 0, (size_t)NF*4, stream);
    scatter_add_kernel<<<E2N/4, 256, 0, stream>>>(abuf, mb, src2, dst2);
    gemm_nt<384,0><<<gN, 256, smemK(128,384), stream>>>(abuf, nullptr, nullptr, nullptr, 128,
        WTb + O_GRUWIH, gru_bih, gi, 128, 0);
    gemm_nt<384,0><<<gN, 256, smemK(128,384), stream>>>(hh, nullptr, nullptr, nullptr, 128,
        WTb + O_GRUWHH, gru_bhh, gh, 128, 0);
    gru_update_kernel<<<NF/256, 256, 0, stream>>>(hh, gi, gh);
  }
  ln_lrelu_kernel<<<NN, 128, 0, stream>>>(hnf, hh, res, hn_g, hn_b);
  segmean_kernel<<<BB, 128, 0, stream>>>(hg2m, hnf, nullptr);

  for (int l=0; l<2; ++l) {
    const int i0 = l*2 + 0, i1 = l*2 + 1;
    gemm_nt<512,0><<<gN, 256, smemK(128,512), stream>>>(ha, nullptr, nullptr, nullptr, 128,
        WTb + O_LSTMWIH + i0*65536, bsum + i0*512, Gx, 128, 0);
    gemm_nt<512,0><<<gN, 256, smemK(128,512), stream>>>(hd, nullptr, nullptr, nullptr, 128,
        WTb + O_LSTMWIH + i1*65536, bsum + i1*512, Gx + (size_t)NN*512, 128, 0);
    lstm_kernel<<<(2*NN)/32, 256, 0, stream>>>(hLb, Gx, nbr_a2d, nbr_d2a,
        WTb + O_LSTMWHH + i0*65536, WTb + O_LSTMWHH + i1*65536);
    gemm_nt<128,0><<<gN, 256, smemK(128,128), stream>>>(hd, nullptr, nullptr, nullptr, 128,
        WTb + O_FCS + i0*16384, fcs_b + i0*128, nd, 128, 0);
    gemm_nt<128,0><<<gN, 256, smemK(128,128), stream>>>(hLb, nullptr, nullptr, nullptr, 128,
        WTb + O_FCN + i0*16384, fcn_b + i0*128, nd, 128, 1);
    gemm_nt<128,0><<<gN, 256, smemK(128,128), stream>>>(ha, nullptr, nullptr, nullptr, 128,
        WTb + O_FCS + i1*16384, fcs_b + i1*128, na, 128, 0);
    gemm_nt<128,0><<<gN, 256, smemK(128,128), stream>>>(hLb + (size_t)NN*128, nullptr, nullptr, nullptr, 128,
        WTb + O_FCN + i1*16384, fcn_b + i1*128, na, 128, 1);
    ln_lrelu_kernel<<<NN, 128, 0, stream>>>(na, na, nullptr, n1_g + i0*128, n1_b + i0*128);
    ln_lrelu_kernel<<<NN, 128, 0, stream>>>(nd, nd, nullptr, n1_g + i1*128, n1_b + i1*128);
    ln_lrelu_kernel<<<NN, 128, 0, stream>>>(ha, ha, na, n3_g + i0*128, n3_b + i0*128);
    ln_lrelu_kernel<<<NN, 128, 0, stream>>>(hd, hd, nd, n3_g + i1*128, n3_b + i1*128);
  }
  segmean_kernel<<<BB, 128, 0, stream>>>(hgm, ha, hd);

  gemm_nt<128,1><<<gB, 256, smemK(128,128), stream>>>(hg2m, nullptr, nullptr, nullptr, 128,
      WTb + O_MO1, mo_b1, t1b, 128, 0);
  gemm_nt<128,1><<<gB, 256, smemK(128,128), stream>>>(t1b, nullptr, nullptr, nullptr, 128,
      WTb + O_MO2, mo_b2, o1b, 128, 0);
  gemm_nt<128,1><<<gB, 256, smemK(128,128), stream>>>(hgm, nullptr, nullptr, nullptr, 128,
      WTb + O_MH1, mh_b1, t2b, 128, 0);
  gemm_nt<128,1><<<gB, 256, smemK(128,128), stream>>>(t2b, nullptr, nullptr, nullptr, 128,
      WTb + O_MH2, mh_b2, o2b, 128, 0);
  gemm_nt<256,0><<<gB, 256, smemK(256,256), stream>>>(o1b, hg2m, nullptr, nullptr, 128,
      WTb + O_MLP1, nullptr, h1b, 256, 0);
  gemm_nt<256,1><<<gB, 256, smemK(256,256), stream>>>(o2b, hgm, nullptr, nullptr, 128,
      WTb + O_MLP1 + 256*256, mlp_b1, h1b, 256, 1);
  gemm_nt<128,1><<<gB, 256, smemK(256,128), stream>>>(h1b, h1b + 128, nullptr, nullptr, 256,
      WTb + O_MLP2, mlp_b2, h2b, 256, 0);
  cls_kernel<<<10, 256, 0, stream>>>((float*)d_out, h2b, cls_W, cls_b);
}

// Round 3
// 5643.760 us; speedup vs baseline: 1.0094x; 1.0094x over previous
//
#include <hip/hip_runtime.h>
#include <math.h>

#define NN 32768
#define HH 128
#define DD 16
#define BB 256
#define E2N (NN*DD)
#define NF (NN*HH)

__device__ __forceinline__ float fsig(float x) { return 1.0f/(1.0f + __expf(-x)); }
__device__ __forceinline__ float ftanh(float x) {
  float cx = fminf(fmaxf(x, -15.0f), 15.0f);
  float e = __expf(2.0f*cx);
  return 1.0f - 2.0f/(e + 1.0f);
}

__device__ __forceinline__ void gload_lds16(const float* g, float* l) {
  __builtin_amdgcn_global_load_lds((const __attribute__((address_space(1))) void*)g,
                                   (__attribute__((address_space(3))) void*)l, 16, 0, 0);
}

// ---------------- transpose prep (all weights -> [K][Nout] layout) ----------------
struct TDesc { const float* src; float* dst; int R; int C; };
struct TDescArr { TDesc d[26]; };

__global__ void transpose_many(TDescArr da) {
  TDesc t = da.d[blockIdx.y];
  int idx = blockIdx.x*256 + threadIdx.x;
  if (idx < t.R*t.C) {
    int r = idx / t.C, c = idx - r*t.C;
    t.dst[(size_t)c*t.R + r] = t.src[idx];
  }
}

__global__ void bias_sum_kernel(const float* __restrict__ bih, const float* __restrict__ bhh,
                                float* __restrict__ bsum) {
  int i = blockIdx.x*256 + threadIdx.x;
  if (i < 2048) bsum[i] = bih[i] + bhh[i];
}

// ---------------- embeddings ----------------
__global__ void embed3_kernel(const int* __restrict__ a_ids, const int* __restrict__ d_ids,
                              const int* __restrict__ a2_ids,
                              const float* __restrict__ ea, const float* __restrict__ ed,
                              const float* __restrict__ ea2,
                              float* __restrict__ ha, float* __restrict__ hd,
                              float* __restrict__ hg2) {
  int idx = blockIdx.x*256 + threadIdx.x;
  int n = idx >> 7, j = idx & 127;
  int w = blockIdx.y;
  if (w == 0)      ha[idx]  = ea[(size_t)a_ids[n]*128 + j];
  else if (w == 1) hd[idx]  = ed[(size_t)d_ids[n]*128 + j];
  else             hg2[idx] = ea2[(size_t)a2_ids[n]*128 + j];
}

// ---------------- generic GEMM: C = act(A @ W^T + bias + beta*C) ----------------
template<int BN, int ACT>
__global__ __launch_bounds__(256) void gemm_nt(
    const float* __restrict__ A0, const float* __restrict__ A1,
    const float* __restrict__ A2, const float* __restrict__ A3,
    int lda, const float* __restrict__ WT, const float* __restrict__ bias,
    float* __restrict__ C, int K, int beta)
{
  extern __shared__ float sm[];
  const int KP = K + 4;
  float* At = sm;             // [32][KP]
  float* Bc = sm + 32*KP;     // [16][BN]
  const int tid = threadIdx.x;
  const int m0 = blockIdx.x*32;
  const int ng = tid >> 5, cg = tid & 31;
  const int n0 = ng*4, c4 = cg*4;
  constexpr int G = BN/128;
  float acc[G][4][4];
#pragma unroll
  for (int g=0; g<G; ++g)
#pragma unroll
    for (int i=0;i<4;++i)
#pragma unroll
      for (int e=0;e<4;++e) acc[g][i][e] = 0.0f;

  const int nf4 = K >> 2;
  for (int idx = tid; idx < 32*nf4; idx += 256) {
    int row = idx / nf4;
    int kk = (idx - row*nf4) << 2;
    const float* Ap = (kk < 128) ? A0 : (kk < 256) ? A1 : (kk < 384) ? A2 : A3;
    float4 v = *(const float4*)(Ap + (size_t)(m0+row)*lda + (kk & 127));
    *(float4*)(At + row*KP + kk) = v;
  }
  const int nchunk = K >> 4;
  for (int kc = 0; kc < nchunk; ++kc) {
    __syncthreads();
    for (int idx = tid; idx < 16*(BN/4); idx += 256) {
      int kk = idx / (BN/4);
      int jq = idx - kk*(BN/4);
      *(float4*)(Bc + kk*BN + jq*4) = *(const float4*)(WT + (size_t)(kc*16+kk)*BN + jq*4);
    }
    __syncthreads();
    for (int k=0;k<16;++k) {
      const int kk = kc*16 + k;
      float av[4];
#pragma unroll
      for (int i=0;i<4;++i) av[i] = At[(n0+i)*KP + kk];
#pragma unroll
      for (int g=0; g<G; ++g) {
        float4 bv = *(const float4*)(Bc + k*BN + g*128 + c4);
        float bb[4] = {bv.x, bv.y, bv.z, bv.w};
#pragma unroll
        for (int i=0;i<4;++i)
#pragma unroll
          for (int e=0;e<4;++e)
            acc[g][i][e] += av[i]*bb[e];
      }
    }
  }
#pragma unroll
  for (int g=0; g<G; ++g) {
#pragma unroll
    for (int i=0;i<4;++i) {
      float* dst = C + (size_t)(m0+n0+i)*BN + g*128 + c4;
      float o[4];
#pragma unroll
      for (int e=0;e<4;++e) o[e] = acc[g][i][e];
      if (bias) {
#pragma unroll
        for (int e=0;e<4;++e) o[e] += bias[g*128 + c4 + e];
      }
      if (beta) {
        float4 p = *(const float4*)dst;
        o[0]+=p.x; o[1]+=p.y; o[2]+=p.z; o[3]+=p.w;
      }
      if (ACT==1) {
#pragma unroll
        for (int e=0;e<4;++e) o[e] = fmaxf(o[e], 0.0f);
      }
      *(float4*)dst = make_float4(o[0],o[1],o[2],o[3]);
    }
  }
}

// ---------------- persistent LSTM aggregator v3 ----------------
// 32 rows/block, LDS 33.3KB (4 blocks/CU), double-buffered Whh chunks of 4 k
// staged via global_load_lds (prefetch kc+1 during compute of kc).
// No min-waves hint (v2's (256,4) made the allocator target the 64-VGPR step
// and spill 492MB of scratch). hv[] removed: activations write h_tile directly,
// final store re-reads h_tile.
__global__ __launch_bounds__(256) void lstm_kernel(
    float* __restrict__ hL, const float* __restrict__ Gx,
    const int* __restrict__ nbrA, const int* __restrict__ nbrD,
    const float* __restrict__ WT0, const float* __restrict__ WT1)
{
  __shared__ float h_tile[32*132];      // 16896 B
  __shared__ float Bc[2*4*512];         // 16384 B (double-buffered [4][512])
  const int tid = threadIdx.x;
  const int r0 = blockIdx.x*32;
  const bool dir = (r0 >= NN);
  const int* nbr = dir ? nbrD : nbrA;
  const int nb = dir ? (r0 - NN) : r0;
  const float* gxb = Gx + (dir ? (size_t)NN*512 : (size_t)0);
  const float* WT = dir ? WT1 : WT0;
  const int ng = tid >> 5, cg = tid & 31;
  const int n0 = ng*4, c4 = cg*4;
  float cst[4][4];
#pragma unroll
  for (int i=0;i<4;++i)
#pragma unroll
    for (int e=0;e<4;++e) cst[i][e] = 0.0f;

  // prologue: stage chunk 0 (for t=1) into buf0
  {
    const float* g0 = WT + tid*4;
    float* l0 = (float*)Bc + tid*4;
    gload_lds16(g0, l0);
    gload_lds16(g0 + 1024, l0 + 1024);
  }

  for (int t=0; t<16; ++t) {
    float acc[4][4][4];   // [gate][node][elem]
    // gather precomputed input-gate pre-activations (serves as acc init)
#pragma unroll
    for (int i=0;i<4;++i) {
      const int gr = nbr[(size_t)(nb + n0 + i)*DD + t];
      const float* row = gxb + (size_t)gr*512;
#pragma unroll
      for (int g=0; g<4; ++g) {
        float4 v = *(const float4*)(row + g*128 + c4);
        acc[g][i][0]=v.x; acc[g][i][1]=v.y; acc[g][i][2]=v.z; acc[g][i][3]=v.w;
      }
    }
    if (t > 0) {
      for (int kc=0; kc<32; ++kc) {
        __syncthreads();   // buf[kc&1] staged; prior chunk's reads drained
        if (kc < 31) {     // prefetch chunk kc+1 into buf^1 (overlaps compute)
          const float* gsrc = WT + (kc+1)*2048 + tid*4;
          float* ldst = (float*)Bc + ((kc+1)&1)*2048 + tid*4;
          gload_lds16(gsrc, ldst);
          gload_lds16(gsrc + 1024, ldst + 1024);
        }
        const float* Bp = Bc + (kc&1)*2048;
        float4 av4[4];
#pragma unroll
        for (int i=0;i<4;++i)
          av4[i] = *(const float4*)(h_tile + (n0+i)*132 + kc*4);
#pragma unroll
        for (int k=0;k<4;++k) {
          float avk[4];
#pragma unroll
          for (int i=0;i<4;++i)
            avk[i] = (k==0) ? av4[i].x : (k==1) ? av4[i].y : (k==2) ? av4[i].z : av4[i].w;
#pragma unroll
          for (int g=0;g<4;++g) {
            float4 bv = *(const float4*)(Bp + k*512 + g*128 + c4);
            float bb[4] = {bv.x,bv.y,bv.z,bv.w};
#pragma unroll
            for (int i=0;i<4;++i)
#pragma unroll
              for (int e=0;e<4;++e)
                acc[g][i][e] += avk[i]*bb[e];
          }
        }
      }
    }
    __syncthreads();   // all h_tile reads for this step done
#pragma unroll
    for (int i=0;i<4;++i) {
      float hv0[4];
#pragma unroll
      for (int e=0;e<4;++e) {
        float ig = fsig(acc[0][i][e]);
        float fg = fsig(acc[1][i][e]);
        float gg = ftanh(acc[2][i][e]);
        float og = fsig(acc[3][i][e]);
        float cc = fg*cst[i][e] + ig*gg;
        cst[i][e] = cc;
        hv0[e] = og*ftanh(cc);
      }
      *(float4*)(h_tile + (n0+i)*132 + c4) = make_float4(hv0[0],hv0[1],hv0[2],hv0[3]);
    }
    if (t > 0 && t < 15) {   // re-stage chunk 0 for next step into buf0
      const float* g0 = WT + tid*4;
      float* l0 = (float*)Bc + tid*4;
      gload_lds16(g0, l0);
      gload_lds16(g0 + 1024, l0 + 1024);
    }
    __syncthreads();   // h_tile writes + chunk-0 staging visible
  }
  // final hidden state: read back from h_tile (saves 16 VGPRs vs hv array)
#pragma unroll
  for (int i=0;i<4;++i) {
    float4 v = *(const float4*)(h_tile + (n0+i)*132 + c4);
    *(float4*)(hL + (size_t)(r0+n0+i)*HH + c4) = v;
  }
}

// ---------------- GGC scatter-add: a[dst] += m[src] (128 floats/edge) ----------------
__global__ void scatter_add_kernel(float* __restrict__ a, const float* __restrict__ m,
                                   const int* __restrict__ src, const int* __restrict__ dst) {
  int wid = (blockIdx.x*256 + threadIdx.x) >> 6;
  int lane = threadIdx.x & 63;
  int s = src[wid], d = dst[wid];
  const float* mr = m + (size_t)s*128;
  float* ar = a + (size_t)d*128;
  atomicAdd(ar + lane, mr[lane]);
  atomicAdd(ar + 64 + lane, mr[64 + lane]);
}

// ---------------- GRU pointwise ----------------
__global__ void gru_update_kernel(float* __restrict__ hh, const float* __restrict__ gi,
                                  const float* __restrict__ gh) {
  int idx = blockIdx.x*256 + threadIdx.x;
  int n = idx >> 7, j = idx & 127;
  const float* gin = gi + (size_t)n*384;
  const float* ghn = gh + (size_t)n*384;
  float r  = fsig(gin[j] + ghn[j]);
  float z  = fsig(gin[128+j] + ghn[128+j]);
  float nn2 = ftanh(gin[256+j] + r*ghn[256+j]);
  float h = hh[idx];
  hh[idx] = (1.0f - z)*nn2 + z*h;
}

// ---------------- LayerNorm (+optional residual add) + leaky relu ----------------
__global__ void ln_lrelu_kernel(float* __restrict__ out, const float* __restrict__ x,
                                const float* __restrict__ add,
                                const float* __restrict__ g, const float* __restrict__ b) {
  int n = blockIdx.x, j = threadIdx.x;   // 128 threads
  size_t base = (size_t)n*128;
  float v = x[base+j];
  if (add) v += add[base+j];
  __shared__ float sh[4];
  float s = v;
#pragma unroll
  for (int m=32; m>=1; m>>=1) s += __shfl_xor(s, m, 64);
  if ((j&63)==0) sh[j>>6] = s;
  __syncthreads();
  float mean = (sh[0]+sh[1]) * 0.0078125f;
  float d = v - mean;
  float q = d*d;
#pragma unroll
  for (int m=32; m>=1; m>>=1) q += __shfl_xor(q, m, 64);
  if ((j&63)==0) sh[2+(j>>6)] = q;
  __syncthreads();
  float var = (sh[2]+sh[3]) * 0.0078125f;
  float y = d * rsqrtf(var + 1e-5f) * g[j] + b[j];
  out[base+j] = (y >= 0.0f) ? y : 0.01f*y;
}

// ---------------- segment mean (contiguous 128-node segments) ----------------
__global__ void segmean_kernel(float* __restrict__ out, const float* __restrict__ x,
                               const float* __restrict__ y) {
  int b = blockIdx.x, j = threadIdx.x;   // 128 threads, 256 blocks
  float s = 0.0f;
  for (int r=0; r<128; ++r) {
    size_t n = (size_t)(b*128 + r)*128 + j;
    s += x[n];
    if (y) s += y[n];
  }
  out[(size_t)b*128 + j] = s * 0.0078125f;
}

// ---------------- classifier head ----------------
__global__ void cls_kernel(float* __restrict__ out, const float* __restrict__ h2,
                           const float* __restrict__ Wc, const float* __restrict__ bc) {
  int gid = blockIdx.x*256 + threadIdx.x;
  if (gid >= BB*10) return;
  int mrow = gid/10, c = gid - mrow*10;
  const float* arow = h2 + (size_t)mrow*128;
  const float* wrow = Wc + (size_t)c*128;
  float s = bc[c];
  for (int k=0;k<128;++k) s += arow[k]*wrow[k];
  out[gid] = s;
}

__global__ void bail_kernel(float* out, float v) {
  if (threadIdx.x==0 && blockIdx.x==0) out[0] = v;
}

// ---------------- host orchestration ----------------
extern "C" void kernel_launch(void* const* d_in, const int* in_sizes, int n_in,
                              void* d_out, int out_size, void* d_ws, size_t ws_size,
                              hipStream_t stream)
{
  const int* act_ids  = (const int*)d_in[0];
  const int* dur_ids  = (const int*)d_in[1];
  const int* act2_ids = (const int*)d_in[2];
  const int* nbr_a2d  = (const int*)d_in[3];
  const int* nbr_d2a  = (const int*)d_in[4];
  const int* src2     = (const int*)d_in[5];
  const int* dst2     = (const int*)d_in[6];
  const float* emb_act     = (const float*)d_in[8];
  const float* emb_dur     = (const float*)d_in[9];
  const float* emb_act2    = (const float*)d_in[10];
  const float* transform_W = (const float*)d_in[11];
  const float* transform_b = (const float*)d_in[12];
  const float* ggc_W   = (const float*)d_in[13];
  const float* ggc_b   = (const float*)d_in[14];
  const float* gru_Wih = (const float*)d_in[15];
  const float* gru_Whh = (const float*)d_in[16];
  const float* gru_bih = (const float*)d_in[17];
  const float* gru_bhh = (const float*)d_in[18];
  const float* hn_g    = (const float*)d_in[19];
  const float* hn_b    = (const float*)d_in[20];
  const float* lstm_Wih = (const float*)d_in[21];
  const float* lstm_Whh = (const float*)d_in[22];
  const float* lstm_bih = (const float*)d_in[23];
  const float* lstm_bhh = (const float*)d_in[24];
  const float* fcs_W = (const float*)d_in[25];
  const float* fcs_b = (const float*)d_in[26];
  const float* fcn_W = (const float*)d_in[27];
  const float* fcn_b = (const float*)d_in[28];
  const float* n1_g = (const float*)d_in[29];
  const float* n1_b = (const float*)d_in[30];
  const float* n3_g = (const float*)d_in[31];
  const float* n3_b = (const float*)d_in[32];
  const float* mh_W1 = (const float*)d_in[33];
  const float* mh_b1 = (const float*)d_in[34];
  const float* mh_W2 = (const float*)d_in[35];
  const float* mh_b2 = (const float*)d_in[36];
  const float* mo_W1 = (const float*)d_in[37];
  const float* mo_b1 = (const float*)d_in[38];
  const float* mo_W2 = (const float*)d_in[39];
  const float* mo_b2 = (const float*)d_in[40];
  const float* mlp_W1 = (const float*)d_in[41];
  const float* mlp_b1 = (const float*)d_in[42];
  const float* mlp_W2 = (const float*)d_in[43];
  const float* mlp_b2 = (const float*)d_in[44];
  const float* cls_W = (const float*)d_in[45];
  const float* cls_b = (const float*)d_in[46];

  float* ws = (float*)d_ws;
  float* ha   = ws;
  float* hd   = ws + (size_t)NF;
  float* hg2  = ws + 2*(size_t)NF;
  float* res  = ws + 3*(size_t)NF;
  float* hh   = ws + 4*(size_t)NF;
  float* SCR  = ws + 5*(size_t)NF;
  float* mb   = SCR;
  float* abuf = SCR + (size_t)NF;
  float* gi   = SCR + 2*(size_t)NF;
  float* gh   = SCR + 5*(size_t)NF;
  float* hnf  = mb;
  float* Gx   = SCR;
  float* hLb  = SCR + 8*(size_t)NF;
  float* SMALL = ws + 15*(size_t)NF;
  float* hg2m = SMALL;
  float* hgm  = SMALL + 32768;
  float* o1b  = SMALL + 65536;
  float* o2b  = SMALL + 98304;
  float* t1b  = SMALL + 131072;
  float* t2b  = SMALL + 163840;
  float* h1b  = SMALL + 196608;
  float* h2b  = SMALL + 262144;
  float* bsum = SMALL + 294912;
  float* WTb  = SMALL + 296960;
  const size_t NEED_BYTES = (size_t)(15*(size_t)NF + 296960 + 1032192) * 4;
  if (ws_size < NEED_BYTES) {
    hipMemsetAsync(d_out, 0, (size_t)out_size*sizeof(float), stream);
    bail_kernel<<<1,64,0,stream>>>((float*)d_out, (float)ws_size);
    return;
  }
  float* na = hg2;
  float* nd = res;

  const int O_TRANSFORM = 0;
  const int O_GGC      = 32768;
  const int O_GRUWIH   = 49152;
  const int O_GRUWHH   = 98304;
  const int O_LSTMWIH  = 147456;
  const int O_LSTMWHH  = 409600;
  const int O_FCS      = 671744;
  const int O_FCN      = 737280;
  const int O_MH1      = 802816;
  const int O_MH2      = 819200;
  const int O_MO1      = 835584;
  const int O_MO2      = 851968;
  const int O_MLP1     = 868352;
  const int O_MLP2     = 999424;

  TDescArr da;
  int di = 0;
  auto addT = [&](const float* s, float* d, int R, int C){ da.d[di].src=s; da.d[di].dst=d; da.d[di].R=R; da.d[di].C=C; ++di; };
  addT(transform_W, WTb + O_TRANSFORM, 128, 256);
  addT(ggc_W,   WTb + O_GGC,    128, 128);
  addT(gru_Wih, WTb + O_GRUWIH, 384, 128);
  addT(gru_Whh, WTb + O_GRUWHH, 384, 128);
  for (int i=0;i<4;++i) addT(lstm_Wih + (size_t)i*65536, WTb + O_LSTMWIH + i*65536, 512, 128);
  for (int i=0;i<4;++i) addT(lstm_Whh + (size_t)i*65536, WTb + O_LSTMWHH + i*65536, 512, 128);
  for (int i=0;i<4;++i) addT(fcs_W + (size_t)i*16384, WTb + O_FCS + i*16384, 128, 128);
  for (int i=0;i<4;++i) addT(fcn_W + (size_t)i*16384, WTb + O_FCN + i*16384, 128, 128);
  addT(mh_W1, WTb + O_MH1, 128, 128);
  addT(mh_W2, WTb + O_MH2, 128, 128);
  addT(mo_W1, WTb + O_MO1, 128, 128);
  addT(mo_W2, WTb + O_MO2, 128, 128);
  addT(mlp_W1, WTb + O_MLP1, 256, 512);
  addT(mlp_W2, WTb + O_MLP2, 128, 256);
  transpose_many<<<dim3(512, 26), 256, 0, stream>>>(da);
  bias_sum_kernel<<<8, 256, 0, stream>>>(lstm_bih, lstm_bhh, bsum);

  auto smemK = [](int K, int BN){ return (size_t)(32*(K+4) + 16*BN)*4; };
  const int gN = NN/32;
  const int gB = BB/32;

  embed3_kernel<<<dim3(NF/256, 3), 256, 0, stream>>>(act_ids, dur_ids, act2_ids,
      emb_act, emb_dur, emb_act2, ha, hd, hg2);
  gemm_nt<128,0><<<gN, 256, smemK(256,128), stream>>>(hg2, hd, nullptr, nullptr, 128,
      WTb + O_TRANSFORM, transform_b, res, 256, 0);
  hipMemcpyAsync(hh, res, (size_t)NF*4, hipMemcpyDeviceToDevice, stream);

  for (int it=0; it<2; ++it) {
    gemm_nt<128,0><<<gN, 256, smemK(128,128), stream>>>(hh, nullptr, nullptr, nullptr, 128,
        WTb + O_GGC, ggc_b, mb, 128, 0);
    hipMemsetAsync(abuf, 0, (size_t)NF*4, stream);
    scatter_add_kernel<<<E2N/4, 256, 0, stream>>>(abuf, mb, src2, dst2);
    gemm_nt<384,0><<<gN, 256, smemK(128,384), stream>>>(abuf, nullptr, nullptr, nullptr, 128,
        WTb + O_GRUWIH, gru_bih, gi, 128, 0);
    gemm_nt<384,0><<<gN, 256, smemK(128,384), stream>>>(hh, nullptr, nullptr, nullptr, 128,
        WTb + O_GRUWHH, gru_bhh, gh, 128, 0);
    gru_update_kernel<<<NF/256, 256, 0, stream>>>(hh, gi, gh);
  }
  ln_lrelu_kernel<<<NN, 128, 0, stream>>>(hnf, hh, res, hn_g, hn_b);
  segmean_kernel<<<BB, 128, 0, stream>>>(hg2m, hnf, nullptr);

  for (int l=0; l<2; ++l) {
    const int i0 = l*2 + 0, i1 = l*2 + 1;
    gemm_nt<512,0><<<gN, 256, smemK(128,512), stream>>>(ha, nullptr, nullptr, nullptr, 128,
        WTb + O_LSTMWIH + i0*65536, bsum + i0*512, Gx, 128, 0);
    gemm_nt<512,0><<<gN, 256, smemK(128,512), stream>>>(hd, nullptr, nullptr, nullptr, 128,
        WTb + O_LSTMWIH + i1*65536, bsum + i1*512, Gx + (size_t)NN*512, 128, 0);
    lstm_kernel<<<(2*NN)/32, 256, 0, stream>>>(hLb, Gx, nbr_a2d, nbr_d2a,
        WTb + O_LSTMWHH + i0*65536, WTb + O_LSTMWHH + i1*65536);
    gemm_nt<128,0><<<gN, 256, smemK(128,128), stream>>>(hd, nullptr, nullptr, nullptr, 128,
        WTb + O_FCS + i0*16384, fcs_b + i0*128, nd, 128, 0);
    gemm_nt<128,0><<<gN, 256, smemK(128,128), stream>>>(hLb, nullptr, nullptr, nullptr, 128,
        WTb + O_FCN + i0*16384, fcn_b + i0*128, nd, 128, 1);
    gemm_nt<128,0><<<gN, 256, smemK(128,128), stream>>>(ha, nullptr, nullptr, nullptr, 128,
        WTb + O_FCS + i1*16384, fcs_b + i1*128, na, 128, 0);
    gemm_nt<128,0><<<gN, 256, smemK(128,128), stream>>>(hLb + (size_t)NN*128, nullptr, nullptr, nullptr, 128,
        WTb + O_FCN + i1*16384, fcn_b + i1*128, na, 128, 1);
    ln_lrelu_kernel<<<NN, 128, 0, stream>>>(na, na, nullptr, n1_g + i0*128, n1_b + i0*128);
    ln_lrelu_kernel<<<NN, 128, 0, stream>>>(nd, nd, nullptr, n1_g + i1*128, n1_b + i1*128);
    ln_lrelu_kernel<<<NN, 128, 0, stream>>>(ha, ha, na, n3_g + i0*128, n3_b + i0*128);
    ln_lrelu_kernel<<<NN, 128, 0, stream>>>(hd, hd, nd, n3_g + i1*128, n3_b + i1*128);
  }
  segmean_kernel<<<BB, 128, 0, stream>>>(hgm, ha, hd);

  gemm_nt<128,1><<<gB, 256, smemK(128,128), stream>>>(hg2m, nullptr, nullptr, nullptr, 128,
      WTb + O_MO1, mo_b1, t1b, 128, 0);
  gemm_nt<128,1><<<gB, 256, smemK(128,128), stream>>>(t1b, nullptr, nullptr, nullptr, 128,
      WTb + O_MO2, mo_b2, o1b, 128, 0);
  gemm_nt<128,1><<<gB, 256, smemK(128,128), stream>>>(hgm, nullptr, nullptr, nullptr, 128,
      WTb + O_MH1, mh_b1, t2b, 128, 0);
  gemm_nt<128,1><<<gB, 256, smemK(128,128), stream>>>(t2b, nullptr, nullptr, nullptr, 128,
      WTb + O_MH2, mh_b2, o2b, 128, 0);
  gemm_nt<256,0><<<gB, 256, smemK(256,256), stream>>>(o1b, hg2m, nullptr, nullptr, 128,
      WTb + O_MLP1, nullptr, h1b, 256, 0);
  gemm_nt<256,1><<<gB, 256, smemK(256,256), stream>>>(o2b, hgm, nullptr, nullptr, 128,
      WTb + O_MLP1 + 256*256, mlp_b1, h1b, 256, 1);
  gemm_nt<128,1><<<gB, 256, smemK(256,128), stream>>>(h1b, h1b + 128, nullptr, nullptr, 256,
      WTb + O_MLP2, mlp_b2, h2b, 256, 0);
  cls_kernel<<<10, 256, 0, stream>>>((float*)d_out, h2b, cls_W, cls_b);
}

// Round 4
// 4797.803 us; speedup vs baseline: 1.1873x; 1.1763x over previous
//
#include <hip/hip_runtime.h>
#include <math.h>

#define NN 32768
#define HH 128
#define DD 16
#define BB 256
#define E2N (NN*DD)
#define NF (NN*HH)

typedef __attribute__((ext_vector_type(8))) short bf16x8;
typedef __attribute__((ext_vector_type(4))) short bf16x4;
typedef __attribute__((ext_vector_type(4))) float f32x4;

__device__ __forceinline__ float fsig(float x) { return 1.0f/(1.0f + __expf(-x)); }
__device__ __forceinline__ float ftanh(float x) {
  float cx = fminf(fmaxf(x, -15.0f), 15.0f);
  float e = __expf(2.0f*cx);
  return 1.0f - 2.0f/(e + 1.0f);
}

// round-to-nearest-even fp32 -> bf16 (top 16 bits)
__device__ __forceinline__ unsigned bf16_rne(float x) {
  unsigned u = __float_as_uint(x);
  return (u + 0x7FFFu + ((u >> 16) & 1u)) >> 16;
}
__device__ __forceinline__ void bsplit(float x, short& hi, short& lo) {
  unsigned hb = bf16_rne(x);
  float hf = __uint_as_float(hb << 16);
  hi = (short)hb;
  lo = (short)bf16_rne(x - hf);
}

// ---------------- transpose prep (weights -> [K][Nout] layout) ----------------
struct TDesc { const float* src; float* dst; int R; int C; };
struct TDescArr { TDesc d[26]; };

__global__ void transpose_many(TDescArr da) {
  TDesc t = da.d[blockIdx.y];
  int idx = blockIdx.x*256 + threadIdx.x;
  if (idx < t.R*t.C) {
    int r = idx / t.C, c = idx - r*t.C;
    t.dst[(size_t)c*t.R + r] = t.src[idx];
  }
}

__global__ void bias_sum_kernel(const float* __restrict__ bih, const float* __restrict__ bhh,
                                float* __restrict__ bsum) {
  int i = blockIdx.x*256 + threadIdx.x;
  if (i < 2048) bsum[i] = bih[i] + bhh[i];
}

// split all 4 Whh matrices [512][128] fp32 -> bf16 hi/lo (same layout)
__global__ void whh_split_kernel(const float* __restrict__ W,
                                 short* __restrict__ hi, short* __restrict__ lo) {
  int i = blockIdx.x*256 + threadIdx.x;   // 4*512*128 elems
  short h, l;
  bsplit(W[i], h, l);
  hi[i] = h; lo[i] = l;
}

// ---------------- embeddings ----------------
__global__ void embed3_kernel(const int* __restrict__ a_ids, const int* __restrict__ d_ids,
                              const int* __restrict__ a2_ids,
                              const float* __restrict__ ea, const float* __restrict__ ed,
                              const float* __restrict__ ea2,
                              float* __restrict__ ha, float* __restrict__ hd,
                              float* __restrict__ hg2) {
  int idx = blockIdx.x*256 + threadIdx.x;
  int n = idx >> 7, j = idx & 127;
  int w = blockIdx.y;
  if (w == 0)      ha[idx]  = ea[(size_t)a_ids[n]*128 + j];
  else if (w == 1) hd[idx]  = ed[(size_t)d_ids[n]*128 + j];
  else             hg2[idx] = ea2[(size_t)a2_ids[n]*128 + j];
}

// ---------------- generic GEMM: C = act(A @ W^T + bias + beta*C) ----------------
template<int BN, int ACT>
__global__ __launch_bounds__(256) void gemm_nt(
    const float* __restrict__ A0, const float* __restrict__ A1,
    const float* __restrict__ A2, const float* __restrict__ A3,
    int lda, const float* __restrict__ WT, const float* __restrict__ bias,
    float* __restrict__ C, int K, int beta)
{
  extern __shared__ float sm[];
  const int KP = K + 4;
  float* At = sm;             // [32][KP]
  float* Bc = sm + 32*KP;     // [16][BN]
  const int tid = threadIdx.x;
  const int m0 = blockIdx.x*32;
  const int ng = tid >> 5, cg = tid & 31;
  const int n0 = ng*4, c4 = cg*4;
  constexpr int G = BN/128;
  float acc[G][4][4];
#pragma unroll
  for (int g=0; g<G; ++g)
#pragma unroll
    for (int i=0;i<4;++i)
#pragma unroll
      for (int e=0;e<4;++e) acc[g][i][e] = 0.0f;

  const int nf4 = K >> 2;
  for (int idx = tid; idx < 32*nf4; idx += 256) {
    int row = idx / nf4;
    int kk = (idx - row*nf4) << 2;
    const float* Ap = (kk < 128) ? A0 : (kk < 256) ? A1 : (kk < 384) ? A2 : A3;
    float4 v = *(const float4*)(Ap + (size_t)(m0+row)*lda + (kk & 127));
    *(float4*)(At + row*KP + kk) = v;
  }
  const int nchunk = K >> 4;
  for (int kc = 0; kc < nchunk; ++kc) {
    __syncthreads();
    for (int idx = tid; idx < 16*(BN/4); idx += 256) {
      int kk = idx / (BN/4);
      int jq = idx - kk*(BN/4);
      *(float4*)(Bc + kk*BN + jq*4) = *(const float4*)(WT + (size_t)(kc*16+kk)*BN + jq*4);
    }
    __syncthreads();
    for (int k=0;k<16;++k) {
      const int kk = kc*16 + k;
      float av[4];
#pragma unroll
      for (int i=0;i<4;++i) av[i] = At[(n0+i)*KP + kk];
#pragma unroll
      for (int g=0; g<G; ++g) {
        float4 bv = *(const float4*)(Bc + k*BN + g*128 + c4);
        float bb[4] = {bv.x, bv.y, bv.z, bv.w};
#pragma unroll
        for (int i=0;i<4;++i)
#pragma unroll
          for (int e=0;e<4;++e)
            acc[g][i][e] += av[i]*bb[e];
      }
    }
  }
#pragma unroll
  for (int g=0; g<G; ++g) {
#pragma unroll
    for (int i=0;i<4;++i) {
      float* dst = C + (size_t)(m0+n0+i)*BN + g*128 + c4;
      float o[4];
#pragma unroll
      for (int e=0;e<4;++e) o[e] = acc[g][i][e];
      if (bias) {
#pragma unroll
        for (int e=0;e<4;++e) o[e] += bias[g*128 + c4 + e];
      }
      if (beta) {
        float4 p = *(const float4*)dst;
        o[0]+=p.x; o[1]+=p.y; o[2]+=p.z; o[3]+=p.w;
      }
      if (ACT==1) {
#pragma unroll
        for (int e=0;e<4;++e) o[e] = fmaxf(o[e], 0.0f);
      }
      *(float4*)dst = make_float4(o[0],o[1],o[2],o[3]);
    }
  }
}

// ---------------- MFMA LSTM aggregator (bf16x3 split, fp32-accurate) ----------------
// Per block: 32 nodes, 4 waves. Wave w owns h-cols cc = w*32..w*32+31 over ALL
// 4 gates (outcols g*128+cc) -> cell update is lane-local.
// Computes D[outcol][node] = Whh . h^T via mfma_f32_16x16x32_bf16:
//   A-frag: Whh_hi/lo [512][128] bf16 row-major, lane reads W[outcol][k0..k0+7]
//   B-frag: h-tile LDS [32][136] bf16 (pad 8), lane reads h[node][k0..k0+7]
//   D: row(=outcol) = lq*4+reg, col(=node) = lane&15  [m89-verified mapping]
// 3 MFMAs per tile-kt: hi*hi + hi*lo + lo*hi (fp32 acc) ~= fp32 product.
__global__ __launch_bounds__(256) void lstm_mfma_kernel(
    float* __restrict__ hL, const float* __restrict__ Gx,
    const int* __restrict__ nbrA, const int* __restrict__ nbrD,
    const short* __restrict__ Whi0, const short* __restrict__ Wlo0,
    const short* __restrict__ Whi1, const short* __restrict__ Wlo1)
{
  __shared__ short hhi[32*136];
  __shared__ short hlo[32*136];
  const int tid = threadIdx.x;
  const int w = tid >> 6;        // wave 0..3
  const int lane = tid & 63;
  const int ln16 = lane & 15;
  const int lq = lane >> 4;      // 0..3
  const int r0 = blockIdx.x*32;
  const bool dir = (r0 >= NN);
  const int* nbr = dir ? nbrD : nbrA;
  const int nb = dir ? (r0 - NN) : r0;
  const float* gxb = Gx + (dir ? (size_t)NN*512 : (size_t)0);
  const short* Whi = dir ? Whi1 : Whi0;
  const short* Wlo = dir ? Wlo1 : Wlo0;

  f32x4 acc[4][2][2];   // [gate][p][nt]
  f32x4 cst[2][2];      // [p][nt]
#pragma unroll
  for (int p=0;p<2;++p)
#pragma unroll
    for (int nt=0;nt<2;++nt)
#pragma unroll
      for (int e=0;e<4;++e) cst[p][nt][e] = 0.0f;

  const int abase = (w*32 + ln16)*128 + lq*8;   // A-frag lane base (shorts)

#pragma unroll 1
  for (int t=0; t<16; ++t) {
    // --- gather Gx pre-activations directly into acc (D-frag layout) ---
#pragma unroll
    for (int nt=0; nt<2; ++nt) {
      const int gr = nbr[(nb + nt*16 + ln16)*DD + t];
      const float* row = gxb + (size_t)gr*512 + w*32 + lq*4;
#pragma unroll
      for (int g=0; g<4; ++g)
#pragma unroll
        for (int p=0; p<2; ++p)
          acc[g][p][nt] = *(const f32x4*)(row + g*128 + p*16);
    }
    // --- recurrent term: acc += Whh . h^T (bf16x3) ---
    if (t > 0) {
#pragma unroll
      for (int kt=0; kt<4; ++kt) {
        const int hoff = kt*32 + lq*8;
        bf16x8 bh0 = *(const bf16x8*)(hhi + ln16*136 + hoff);
        bf16x8 bh1 = *(const bf16x8*)(hhi + (ln16+16)*136 + hoff);
        bf16x8 bl0 = *(const bf16x8*)(hlo + ln16*136 + hoff);
        bf16x8 bl1 = *(const bf16x8*)(hlo + (ln16+16)*136 + hoff);
#pragma unroll
        for (int g=0; g<4; ++g) {
#pragma unroll
          for (int p=0; p<2; ++p) {
            const int co = (g*128 + p*16)*128 + kt*32 + abase;
            bf16x8 ah = *(const bf16x8*)(Whi + co);
            bf16x8 al = *(const bf16x8*)(Wlo + co);
            acc[g][p][0] = __builtin_amdgcn_mfma_f32_16x16x32_bf16(ah, bh0, acc[g][p][0], 0,0,0);
            acc[g][p][1] = __builtin_amdgcn_mfma_f32_16x16x32_bf16(ah, bh1, acc[g][p][1], 0,0,0);
            acc[g][p][0] = __builtin_amdgcn_mfma_f32_16x16x32_bf16(ah, bl0, acc[g][p][0], 0,0,0);
            acc[g][p][1] = __builtin_amdgcn_mfma_f32_16x16x32_bf16(ah, bl1, acc[g][p][1], 0,0,0);
            acc[g][p][0] = __builtin_amdgcn_mfma_f32_16x16x32_bf16(al, bh0, acc[g][p][0], 0,0,0);
            acc[g][p][1] = __builtin_amdgcn_mfma_f32_16x16x32_bf16(al, bh1, acc[g][p][1], 0,0,0);
          }
        }
      }
    }
    __syncthreads();   // all h reads for this step done (WAR)
    // --- activations + cell update (lane-local: all 4 gates present) ---
#pragma unroll
    for (int p=0; p<2; ++p) {
#pragma unroll
      for (int nt=0; nt<2; ++nt) {
        float hv[4];
#pragma unroll
        for (int e=0; e<4; ++e) {
          float ig = fsig(acc[0][p][nt][e]);
          float fg = fsig(acc[1][p][nt][e]);
          float gg = ftanh(acc[2][p][nt][e]);
          float og = fsig(acc[3][p][nt][e]);
          float cc = fg*cst[p][nt][e] + ig*gg;
          cst[p][nt][e] = cc;
          hv[e] = og*ftanh(cc);
        }
        const int node = nt*16 + ln16;
        const int cc0 = w*32 + p*16 + lq*4;
        if (t < 15) {
          bf16x4 shi, slo;
#pragma unroll
          for (int e=0; e<4; ++e) {
            short h_, l_;
            bsplit(hv[e], h_, l_);
            shi[e] = h_; slo[e] = l_;
          }
          *(bf16x4*)(hhi + node*136 + cc0) = shi;
          *(bf16x4*)(hlo + node*136 + cc0) = slo;
        } else {
          *(float4*)(hL + (size_t)(r0+node)*128 + cc0) =
              make_float4(hv[0], hv[1], hv[2], hv[3]);
        }
      }
    }
    __syncthreads();   // h writes visible before next step's reads (RAW)
  }
}

// ---------------- GGC scatter-add: a[dst] += m[src] (128 floats/edge) ----------------
__global__ void scatter_add_kernel(float* __restrict__ a, const float* __restrict__ m,
                                   const int* __restrict__ src, const int* __restrict__ dst) {
  int wid = (blockIdx.x*256 + threadIdx.x) >> 6;
  int lane = threadIdx.x & 63;
  int s = src[wid], d = dst[wid];
  const float* mr = m + (size_t)s*128;
  float* ar = a + (size_t)d*128;
  atomicAdd(ar + lane, mr[lane]);
  atomicAdd(ar + 64 + lane, mr[64 + lane]);
}

// ---------------- GRU pointwise ----------------
__global__ void gru_update_kernel(float* __restrict__ hh, const float* __restrict__ gi,
                                  const float* __restrict__ gh) {
  int idx = blockIdx.x*256 + threadIdx.x;
  int n = idx >> 7, j = idx & 127;
  const float* gin = gi + (size_t)n*384;
  const float* ghn = gh + (size_t)n*384;
  float r  = fsig(gin[j] + ghn[j]);
  float z  = fsig(gin[128+j] + ghn[128+j]);
  float nn2 = ftanh(gin[256+j] + r*ghn[256+j]);
  float h = hh[idx];
  hh[idx] = (1.0f - z)*nn2 + z*h;
}

// ---------------- LayerNorm (+optional residual add) + leaky relu ----------------
__global__ void ln_lrelu_kernel(float* __restrict__ out, const float* __restrict__ x,
                                const float* __restrict__ add,
                                const float* __restrict__ g, const float* __restrict__ b) {
  int n = blockIdx.x, j = threadIdx.x;   // 128 threads
  size_t base = (size_t)n*128;
  float v = x[base+j];
  if (add) v += add[base+j];
  __shared__ float sh[4];
  float s = v;
#pragma unroll
  for (int m=32; m>=1; m>>=1) s += __shfl_xor(s, m, 64);
  if ((j&63)==0) sh[j>>6] = s;
  __syncthreads();
  float mean = (sh[0]+sh[1]) * 0.0078125f;
  float d = v - mean;
  float q = d*d;
#pragma unroll
  for (int m=32; m>=1; m>>=1) q += __shfl_xor(q, m, 64);
  if ((j&63)==0) sh[2+(j>>6)] = q;
  __syncthreads();
  float var = (sh[2]+sh[3]) * 0.0078125f;
  float y = d * rsqrtf(var + 1e-5f) * g[j] + b[j];
  out[base+j] = (y >= 0.0f) ? y : 0.01f*y;
}

// ---------------- segment mean (contiguous 128-node segments) ----------------
__global__ void segmean_kernel(float* __restrict__ out, const float* __restrict__ x,
                               const float* __restrict__ y) {
  int b = blockIdx.x, j = threadIdx.x;   // 128 threads, 256 blocks
  float s = 0.0f;
  for (int r=0; r<128; ++r) {
    size_t n = (size_t)(b*128 + r)*128 + j;
    s += x[n];
    if (y) s += y[n];
  }
  out[(size_t)b*128 + j] = s * 0.0078125f;
}

// ---------------- classifier head ----------------
__global__ void cls_kernel(float* __restrict__ out, const float* __restrict__ h2,
                           const float* __restrict__ Wc, const float* __restrict__ bc) {
  int gid = blockIdx.x*256 + threadIdx.x;
  if (gid >= BB*10) return;
  int mrow = gid/10, c = gid - mrow*10;
  const float* arow = h2 + (size_t)mrow*128;
  const float* wrow = Wc + (size_t)c*128;
  float s = bc[c];
  for (int k=0;k<128;++k) s += arow[k]*wrow[k];
  out[gid] = s;
}

__global__ void bail_kernel(float* out, float v) {
  if (threadIdx.x==0 && blockIdx.x==0) out[0] = v;
}

// ---------------- host orchestration ----------------
extern "C" void kernel_launch(void* const* d_in, const int* in_sizes, int n_in,
                              void* d_out, int out_size, void* d_ws, size_t ws_size,
                              hipStream_t stream)
{
  const int* act_ids  = (const int*)d_in[0];
  const int* dur_ids  = (const int*)d_in[1];
  const int* act2_ids = (const int*)d_in[2];
  const int* nbr_a2d  = (const int*)d_in[3];
  const int* nbr_d2a  = (const int*)d_in[4];
  const int* src2     = (const int*)d_in[5];
  const int* dst2     = (const int*)d_in[6];
  const float* emb_act     = (const float*)d_in[8];
  const float* emb_dur     = (const float*)d_in[9];
  const float* emb_act2    = (const float*)d_in[10];
  const float* transform_W = (const float*)d_in[11];
  const float* transform_b = (const float*)d_in[12];
  const float* ggc_W   = (const float*)d_in[13];
  const float* ggc_b   = (const float*)d_in[14];
  const float* gru_Wih = (const float*)d_in[15];
  const float* gru_Whh = (const float*)d_in[16];
  const float* gru_bih = (const float*)d_in[17];
  const float* gru_bhh = (const float*)d_in[18];
  const float* hn_g    = (const float*)d_in[19];
  const float* hn_b    = (const float*)d_in[20];
  const float* lstm_Wih = (const float*)d_in[21];
  const float* lstm_Whh = (const float*)d_in[22];
  const float* lstm_bih = (const float*)d_in[23];
  const float* lstm_bhh = (const float*)d_in[24];
  const float* fcs_W = (const float*)d_in[25];
  const float* fcs_b = (const float*)d_in[26];
  const float* fcn_W = (const float*)d_in[27];
  const float* fcn_b = (const float*)d_in[28];
  const float* n1_g = (const float*)d_in[29];
  const float* n1_b = (const float*)d_in[30];
  const float* n3_g = (const float*)d_in[31];
  const float* n3_b = (const float*)d_in[32];
  const float* mh_W1 = (const float*)d_in[33];
  const float* mh_b1 = (const float*)d_in[34];
  const float* mh_W2 = (const float*)d_in[35];
  const float* mh_b2 = (const float*)d_in[36];
  const float* mo_W1 = (const float*)d_in[37];
  const float* mo_b1 = (const float*)d_in[38];
  const float* mo_W2 = (const float*)d_in[39];
  const float* mo_b2 = (const float*)d_in[40];
  const float* mlp_W1 = (const float*)d_in[41];
  const float* mlp_b1 = (const float*)d_in[42];
  const float* mlp_W2 = (const float*)d_in[43];
  const float* mlp_b2 = (const float*)d_in[44];
  const float* cls_W = (const float*)d_in[45];
  const float* cls_b = (const float*)d_in[46];

  float* ws = (float*)d_ws;
  float* ha   = ws;
  float* hd   = ws + (size_t)NF;
  float* hg2  = ws + 2*(size_t)NF;
  float* res  = ws + 3*(size_t)NF;
  float* hh   = ws + 4*(size_t)NF;
  float* SCR  = ws + 5*(size_t)NF;
  float* mb   = SCR;
  float* abuf = SCR + (size_t)NF;
  float* gi   = SCR + 2*(size_t)NF;
  float* gh   = SCR + 5*(size_t)NF;
  float* hnf  = mb;
  float* Gx   = SCR;
  float* hLb  = SCR + 8*(size_t)NF;
  float* SMALL = ws + 15*(size_t)NF;
  float* hg2m = SMALL;
  float* hgm  = SMALL + 32768;
  float* o1b  = SMALL + 65536;
  float* o2b  = SMALL + 98304;
  float* t1b  = SMALL + 131072;
  float* t2b  = SMALL + 163840;
  float* h1b  = SMALL + 196608;
  float* h2b  = SMALL + 262144;
  float* bsum = SMALL + 294912;
  float* WTb  = SMALL + 296960;
  const size_t NEED_BYTES = (size_t)(15*(size_t)NF + 296960 + 1032192) * 4;
  if (ws_size < NEED_BYTES) {
    hipMemsetAsync(d_out, 0, (size_t)out_size*sizeof(float), stream);
    bail_kernel<<<1,64,0,stream>>>((float*)d_out, (float)ws_size);
    return;
  }
  float* na = hg2;
  float* nd = res;

  const int O_TRANSFORM = 0;
  const int O_GGC      = 32768;
  const int O_GRUWIH   = 49152;
  const int O_GRUWHH   = 98304;
  const int O_LSTMWIH  = 147456;
  const int O_LSTMWHH  = 409600;   // reused: Whh bf16 hi/lo arena (262144 floats)
  const int O_FCS      = 671744;
  const int O_FCN      = 737280;
  const int O_MH1      = 802816;
  const int O_MH2      = 819200;
  const int O_MO1      = 835584;
  const int O_MO2      = 851968;
  const int O_MLP1     = 868352;
  const int O_MLP2     = 999424;

  // bf16 split Whh storage inside the (now unused) transposed-Whh region:
  // Whi: 4 mats x 512*128 shorts = 262144 shorts (131072 floats), Wlo after.
  short* Whi = (short*)(WTb + O_LSTMWHH);
  short* Wlo = (short*)(WTb + O_LSTMWHH + 131072);

  TDescArr da;
  int di = 0;
  auto addT = [&](const float* s, float* d, int R, int C){ da.d[di].src=s; da.d[di].dst=d; da.d[di].R=R; da.d[di].C=C; ++di; };
  addT(transform_W, WTb + O_TRANSFORM, 128, 256);
  addT(ggc_W,   WTb + O_GGC,    128, 128);
  addT(gru_Wih, WTb + O_GRUWIH, 384, 128);
  addT(gru_Whh, WTb + O_GRUWHH, 384, 128);
  for (int i=0;i<4;++i) addT(lstm_Wih + (size_t)i*65536, WTb + O_LSTMWIH + i*65536, 512, 128);
  for (int i=0;i<4;++i) addT(fcs_W + (size_t)i*16384, WTb + O_FCS + i*16384, 128, 128);
  for (int i=0;i<4;++i) addT(fcn_W + (size_t)i*16384, WTb + O_FCN + i*16384, 128, 128);
  addT(mh_W1, WTb + O_MH1, 128, 128);
  addT(mh_W2, WTb + O_MH2, 128, 128);
  addT(mo_W1, WTb + O_MO1, 128, 128);
  addT(mo_W2, WTb + O_MO2, 128, 128);
  addT(mlp_W1, WTb + O_MLP1, 256, 512);
  addT(mlp_W2, WTb + O_MLP2, 128, 256);
  transpose_many<<<dim3(512, di), 256, 0, stream>>>(da);
  bias_sum_kernel<<<8, 256, 0, stream>>>(lstm_bih, lstm_bhh, bsum);
  whh_split_kernel<<<(4*512*128)/256, 256, 0, stream>>>(lstm_Whh, Whi, Wlo);

  auto smemK = [](int K, int BN){ return (size_t)(32*(K+4) + 16*BN)*4; };
  const int gN = NN/32;
  const int gB = BB/32;

  embed3_kernel<<<dim3(NF/256, 3), 256, 0, stream>>>(act_ids, dur_ids, act2_ids,
      emb_act, emb_dur, emb_act2, ha, hd, hg2);
  gemm_nt<128,0><<<gN, 256, smemK(256,128), stream>>>(hg2, hd, nullptr, nullptr, 128,
      WTb + O_TRANSFORM, transform_b, res, 256, 0);
  hipMemcpyAsync(hh, res, (size_t)NF*4, hipMemcpyDeviceToDevice, stream);

  for (int it=0; it<2; ++it) {
    gemm_nt<128,0><<<gN, 256, smemK(128,128), stream>>>(hh, nullptr, nullptr, nullptr, 128,
        WTb + O_GGC, ggc_b, mb, 128, 0);
    hipMemsetAsync(abuf, 0, (size_t)NF*4, stream);
    scatter_add_kernel<<<E2N/4, 256, 0, stream>>>(abuf, mb, src2, dst2);
    gemm_nt<384,0><<<gN, 256, smemK(128,384), stream>>>(abuf, nullptr, nullptr, nullptr, 128,
        WTb + O_GRUWIH, gru_bih, gi, 128, 0);
    gemm_nt<384,0><<<gN, 256, smemK(128,384), stream>>>(hh, nullptr, nullptr, nullptr, 128,
        WTb + O_GRUWHH, gru_bhh, gh, 128, 0);
    gru_update_kernel<<<NF/256, 256, 0, stream>>>(hh, gi, gh);
  }
  ln_lrelu_kernel<<<NN, 128, 0, stream>>>(hnf, hh, res, hn_g, hn_b);
  segmean_kernel<<<BB, 128, 0, stream>>>(hg2m, hnf, nullptr);

  for (int l=0; l<2; ++l) {
    const int i0 = l*2 + 0, i1 = l*2 + 1;
    gemm_nt<512,0><<<gN, 256, smemK(128,512), stream>>>(ha, nullptr, nullptr, nullptr, 128,
        WTb + O_LSTMWIH + i0*65536, bsum + i0*512, Gx, 128, 0);
    gemm_nt<512,0><<<gN, 256, smemK(128,512), stream>>>(hd, nullptr, nullptr, nullptr, 128,
        WTb + O_LSTMWIH + i1*65536, bsum + i1*512, Gx + (size_t)NN*512, 128, 0);
    lstm_mfma_kernel<<<(2*NN)/32, 256, 0, stream>>>(hLb, Gx, nbr_a2d, nbr_d2a,
        Whi + i0*65536, Wlo + i0*65536, Whi + i1*65536, Wlo + i1*65536);
    gemm_nt<128,0><<<gN, 256, smemK(128,128), stream>>>(hd, nullptr, nullptr, nullptr, 128,
        WTb + O_FCS + i0*16384, fcs_b + i0*128, nd, 128, 0);
    gemm_nt<128,0><<<gN, 256, smemK(128,128), stream>>>(hLb, nullptr, nullptr, nullptr, 128,
        WTb + O_FCN + i0*16384, fcn_b + i0*128, nd, 128, 1);
    gemm_nt<128,0><<<gN, 256, smemK(128,128), stream>>>(ha, nullptr, nullptr, nullptr, 128,
        WTb + O_FCS + i1*16384, fcs_b + i1*128, na, 128, 0);
    gemm_nt<128,0><<<gN, 256, smemK(128,128), stream>>>(hLb + (size_t)NN*128, nullptr, nullptr, nullptr, 128,
        WTb + O_FCN + i1*16384, fcn_b + i1*128, na, 128, 1);
    ln_lrelu_kernel<<<NN, 128, 0, stream>>>(na, na, nullptr, n1_g + i0*128, n1_b + i0*128);
    ln_lrelu_kernel<<<NN, 128, 0, stream>>>(nd, nd, nullptr, n1_g + i1*128, n1_b + i1*128);
    ln_lrelu_kernel<<<NN, 128, 0, stream>>>(ha, ha, na, n3_g + i0*128, n3_b + i0*128);
    ln_lrelu_kernel<<<NN, 128, 0, stream>>>(hd, hd, nd, n3_g + i1*128, n3_b + i1*128);
  }
  segmean_kernel<<<BB, 128, 0, stream>>>(hgm, ha, hd);

  gemm_nt<128,1><<<gB, 256, smemK(128,128), stream>>>(hg2m, nullptr, nullptr, nullptr, 128,
      WTb + O_MO1, mo_b1, t1b, 128, 0);
  gemm_nt<128,1><<<gB, 256, smemK(128,128), stream>>>(t1b, nullptr, nullptr, nullptr, 128,
      WTb + O_MO2, mo_b2, o1b, 128, 0);
  gemm_nt<128,1><<<gB, 256, smemK(128,128), stream>>>(hgm, nullptr, nullptr, nullptr, 128,
      WTb + O_MH1, mh_b1, t2b, 128, 0);
  gemm_nt<128,1><<<gB, 256, smemK(128,128), stream>>>(t2b, nullptr, nullptr, nullptr, 128,
      WTb + O_MH2, mh_b2, o2b, 128, 0);
  gemm_nt<256,0><<<gB, 256, smemK(256,256), stream>>>(o1b, hg2m, nullptr, nullptr, 128,
      WTb + O_MLP1, nullptr, h1b, 256, 0);
  gemm_nt<256,1><<<gB, 256, smemK(256,256), stream>>>(o2b, hgm, nullptr, nullptr, 128,
      WTb + O_MLP1 + 256*256, mlp_b1, h1b, 256, 1);
  gemm_nt<128,1><<<gB, 256, smemK(256,128), stream>>>(h1b, h1b + 128, nullptr, nullptr, 256,
      WTb + O_MLP2, mlp_b2, h2b, 256, 0);
  cls_kernel<<<10, 256, 0, stream>>>((float*)d_out, h2b, cls_W, cls_b);
}

// Round 5
// 4514.185 us; speedup vs baseline: 1.2619x; 1.0628x over previous
//
#include <hip/hip_runtime.h>
#include <math.h>

#define NN 32768
#define HH 128
#define DD 16
#define BB 256
#define E2N (NN*DD)
#define NF (NN*HH)

typedef __attribute__((ext_vector_type(8))) short bf16x8;
typedef __attribute__((ext_vector_type(4))) short bf16x4;
typedef __attribute__((ext_vector_type(4))) float f32x4;

__device__ __forceinline__ float fsig(float x) { return 1.0f/(1.0f + __expf(-x)); }
__device__ __forceinline__ float ftanh(float x) {
  float cx = fminf(fmaxf(x, -15.0f), 15.0f);
  float e = __expf(2.0f*cx);
  return 1.0f - 2.0f/(e + 1.0f);
}

// round-to-nearest-even fp32 -> bf16 (top 16 bits)
__device__ __forceinline__ unsigned bf16_rne(float x) {
  unsigned u = __float_as_uint(x);
  return (u + 0x7FFFu + ((u >> 16) & 1u)) >> 16;
}
__device__ __forceinline__ void bsplit(float x, short& hi, short& lo) {
  unsigned hb = bf16_rne(x);
  float hf = __uint_as_float(hb << 16);
  hi = (short)hb;
  lo = (short)bf16_rne(x - hf);
}

// ---------------- transpose prep (weights -> [K][Nout] layout) ----------------
struct TDesc { const float* src; float* dst; int R; int C; };
struct TDescArr { TDesc d[26]; };

__global__ void transpose_many(TDescArr da) {
  TDesc t = da.d[blockIdx.y];
  int idx = blockIdx.x*256 + threadIdx.x;
  if (idx < t.R*t.C) {
    int r = idx / t.C, c = idx - r*t.C;
    t.dst[(size_t)c*t.R + r] = t.src[idx];
  }
}

__global__ void bias_sum_kernel(const float* __restrict__ bih, const float* __restrict__ bhh,
                                float* __restrict__ bsum) {
  int i = blockIdx.x*256 + threadIdx.x;
  if (i < 2048) bsum[i] = bih[i] + bhh[i];
}

// split 4 matrices [512][128] fp32 -> bf16 hi/lo (same layout)
__global__ void wsplit_kernel(const float* __restrict__ W,
                              short* __restrict__ hi, short* __restrict__ lo) {
  int i = blockIdx.x*256 + threadIdx.x;   // 4*512*128 elems
  short h, l;
  bsplit(W[i], h, l);
  hi[i] = h; lo[i] = l;
}

// ---------------- embeddings ----------------
__global__ void embed3_kernel(const int* __restrict__ a_ids, const int* __restrict__ d_ids,
                              const int* __restrict__ a2_ids,
                              const float* __restrict__ ea, const float* __restrict__ ed,
                              const float* __restrict__ ea2,
                              float* __restrict__ ha, float* __restrict__ hd,
                              float* __restrict__ hg2) {
  int idx = blockIdx.x*256 + threadIdx.x;
  int n = idx >> 7, j = idx & 127;
  int w = blockIdx.y;
  if (w == 0)      ha[idx]  = ea[(size_t)a_ids[n]*128 + j];
  else if (w == 1) hd[idx]  = ed[(size_t)d_ids[n]*128 + j];
  else             hg2[idx] = ea2[(size_t)a2_ids[n]*128 + j];
}

// ---------------- generic GEMM: C = act(A @ W^T + bias + beta*C) ----------------
template<int BN, int ACT>
__global__ __launch_bounds__(256) void gemm_nt(
    const float* __restrict__ A0, const float* __restrict__ A1,
    const float* __restrict__ A2, const float* __restrict__ A3,
    int lda, const float* __restrict__ WT, const float* __restrict__ bias,
    float* __restrict__ C, int K, int beta)
{
  extern __shared__ float sm[];
  const int KP = K + 4;
  float* At = sm;             // [32][KP]
  float* Bc = sm + 32*KP;     // [16][BN]
  const int tid = threadIdx.x;
  const int m0 = blockIdx.x*32;
  const int ng = tid >> 5, cg = tid & 31;
  const int n0 = ng*4, c4 = cg*4;
  constexpr int G = BN/128;
  float acc[G][4][4];
#pragma unroll
  for (int g=0; g<G; ++g)
#pragma unroll
    for (int i=0;i<4;++i)
#pragma unroll
      for (int e=0;e<4;++e) acc[g][i][e] = 0.0f;

  const int nf4 = K >> 2;
  for (int idx = tid; idx < 32*nf4; idx += 256) {
    int row = idx / nf4;
    int kk = (idx - row*nf4) << 2;
    const float* Ap = (kk < 128) ? A0 : (kk < 256) ? A1 : (kk < 384) ? A2 : A3;
    float4 v = *(const float4*)(Ap + (size_t)(m0+row)*lda + (kk & 127));
    *(float4*)(At + row*KP + kk) = v;
  }
  const int nchunk = K >> 4;
  for (int kc = 0; kc < nchunk; ++kc) {
    __syncthreads();
    for (int idx = tid; idx < 16*(BN/4); idx += 256) {
      int kk = idx / (BN/4);
      int jq = idx - kk*(BN/4);
      *(float4*)(Bc + kk*BN + jq*4) = *(const float4*)(WT + (size_t)(kc*16+kk)*BN + jq*4);
    }
    __syncthreads();
    for (int k=0;k<16;++k) {
      const int kk = kc*16 + k;
      float av[4];
#pragma unroll
      for (int i=0;i<4;++i) av[i] = At[(n0+i)*KP + kk];
#pragma unroll
      for (int g=0; g<G; ++g) {
        float4 bv = *(const float4*)(Bc + k*BN + g*128 + c4);
        float bb[4] = {bv.x, bv.y, bv.z, bv.w};
#pragma unroll
        for (int i=0;i<4;++i)
#pragma unroll
          for (int e=0;e<4;++e)
            acc[g][i][e] += av[i]*bb[e];
      }
    }
  }
#pragma unroll
  for (int g=0; g<G; ++g) {
#pragma unroll
    for (int i=0;i<4;++i) {
      float* dst = C + (size_t)(m0+n0+i)*BN + g*128 + c4;
      float o[4];
#pragma unroll
      for (int e=0;e<4;++e) o[e] = acc[g][i][e];
      if (bias) {
#pragma unroll
        for (int e=0;e<4;++e) o[e] += bias[g*128 + c4 + e];
      }
      if (beta) {
        float4 p = *(const float4*)dst;
        o[0]+=p.x; o[1]+=p.y; o[2]+=p.z; o[3]+=p.w;
      }
      if (ACT==1) {
#pragma unroll
        for (int e=0;e<4;++e) o[e] = fmaxf(o[e], 0.0f);
      }
      *(float4*)dst = make_float4(o[0],o[1],o[2],o[3]);
    }
  }
}

// ---------------- fused MFMA LSTM aggregator (gathers raw fs rows) ----------------
// 64 nodes/block, 8 waves (512 thr). Per step: gather x_t = fs[nbr[n][t]] (512B/node,
// L3-resident 16MB table), bsplit into LDS bf16 hi/lo tiles, then two bf16x3 MFMA
// passes: acc = bias + Wih.x^T + Whh.h^T. Wave w owns h-cols w*16..w*16+15 across
// all 4 gates -> cell update lane-local. D-mapping m89-verified (R4 structure).
__global__ __launch_bounds__(512) void lstm_fused_kernel(
    float* __restrict__ hL,
    const float* __restrict__ fs0, const float* __restrict__ fs1,
    const int* __restrict__ nbrA, const int* __restrict__ nbrD,
    const short* __restrict__ WIhi0, const short* __restrict__ WIlo0,
    const short* __restrict__ WHhi0, const short* __restrict__ WHlo0,
    const short* __restrict__ WIhi1, const short* __restrict__ WIlo1,
    const short* __restrict__ WHhi1, const short* __restrict__ WHlo1,
    const float* __restrict__ bsum0, const float* __restrict__ bsum1)
{
  extern __shared__ short smem[];
  short* xhi = smem;            // [64][136]
  short* xlo = smem + 8704;
  short* hhi = smem + 17408;
  short* hlo = smem + 26112;
  const int tid = threadIdx.x;
  const int w = tid >> 6;          // wave 0..7
  const int lane = tid & 63;
  const int ln16 = lane & 15;
  const int lq = lane >> 4;        // 0..3
  const int b = blockIdx.x;
  const bool dir = (b >= 512);
  const int nb = (dir ? (b - 512) : b) * 64;
  const int* nbr = dir ? nbrD : nbrA;
  const float* fs = dir ? fs1 : fs0;
  const short* WIhi = dir ? WIhi1 : WIhi0;
  const short* WIlo = dir ? WIlo1 : WIlo0;
  const short* WHhi = dir ? WHhi1 : WHhi0;
  const short* WHlo = dir ? WHlo1 : WHlo0;
  const float* bsum = dir ? bsum1 : bsum0;

  f32x4 bias[4];
#pragma unroll
  for (int g=0; g<4; ++g)
    bias[g] = *(const f32x4*)(bsum + g*128 + w*16 + lq*4);

  f32x4 acc[4][4];   // [gate][nt]
  f32x4 cst[4];      // [nt]
#pragma unroll
  for (int nt=0; nt<4; ++nt)
#pragma unroll
    for (int e=0; e<4; ++e) cst[nt][e] = 0.0f;

  const int gr_r = tid >> 3;        // gather row 0..63
  const int gcf  = (tid & 7) * 16;  // float col 0..112
  const int cc0  = w*16 + lq*4;     // this lane's h-col base

#pragma unroll 1
  for (int t=0; t<16; ++t) {
    // ---- gather x_t rows (fp32), split to bf16 hi/lo in LDS ----
    {
      const int grow = nbr[(size_t)(nb + gr_r)*DD + t];
      const float* src = fs + (size_t)grow*128 + gcf;
      float4 v0 = *(const float4*)(src);
      float4 v1 = *(const float4*)(src + 4);
      float4 v2 = *(const float4*)(src + 8);
      float4 v3 = *(const float4*)(src + 12);
      short* dh = xhi + gr_r*136 + gcf;
      short* dl = xlo + gr_r*136 + gcf;
      float vs[4];
      bf16x4 sh, sl;
      vs[0]=v0.x; vs[1]=v0.y; vs[2]=v0.z; vs[3]=v0.w;
#pragma unroll
      for (int e=0;e<4;++e){ short h_,l_; bsplit(vs[e],h_,l_); sh[e]=h_; sl[e]=l_; }
      *(bf16x4*)(dh) = sh; *(bf16x4*)(dl) = sl;
      vs[0]=v1.x; vs[1]=v1.y; vs[2]=v1.z; vs[3]=v1.w;
#pragma unroll
      for (int e=0;e<4;++e){ short h_,l_; bsplit(vs[e],h_,l_); sh[e]=h_; sl[e]=l_; }
      *(bf16x4*)(dh+4) = sh; *(bf16x4*)(dl+4) = sl;
      vs[0]=v2.x; vs[1]=v2.y; vs[2]=v2.z; vs[3]=v2.w;
#pragma unroll
      for (int e=0;e<4;++e){ short h_,l_; bsplit(vs[e],h_,l_); sh[e]=h_; sl[e]=l_; }
      *(bf16x4*)(dh+8) = sh; *(bf16x4*)(dl+8) = sl;
      vs[0]=v3.x; vs[1]=v3.y; vs[2]=v3.z; vs[3]=v3.w;
#pragma unroll
      for (int e=0;e<4;++e){ short h_,l_; bsplit(vs[e],h_,l_); sh[e]=h_; sl[e]=l_; }
      *(bf16x4*)(dh+12) = sh; *(bf16x4*)(dl+12) = sl;
    }
    // ---- init acc with (bih+bhh) ----
#pragma unroll
    for (int g=0; g<4; ++g)
#pragma unroll
      for (int nt=0; nt<4; ++nt)
        acc[g][nt] = bias[g];
    __syncthreads();   // x tile ready; prev h writes ready

    // ---- pass 1: Wih . x^T (bf16x3) ----
#pragma unroll
    for (int kt=0; kt<4; ++kt) {
      const int bo = kt*32 + lq*8;
      bf16x8 bxh[4], bxl[4];
#pragma unroll
      for (int nt=0; nt<4; ++nt) {
        bxh[nt] = *(const bf16x8*)(xhi + (nt*16+ln16)*136 + bo);
        bxl[nt] = *(const bf16x8*)(xlo + (nt*16+ln16)*136 + bo);
      }
#pragma unroll
      for (int g=0; g<4; ++g) {
        const int co = (g*128 + w*16 + ln16)*128 + kt*32 + lq*8;
        bf16x8 ah = *(const bf16x8*)(WIhi + co);
        bf16x8 al = *(const bf16x8*)(WIlo + co);
#pragma unroll
        for (int nt=0; nt<4; ++nt) {
          acc[g][nt] = __builtin_amdgcn_mfma_f32_16x16x32_bf16(ah, bxh[nt], acc[g][nt], 0,0,0);
          acc[g][nt] = __builtin_amdgcn_mfma_f32_16x16x32_bf16(ah, bxl[nt], acc[g][nt], 0,0,0);
          acc[g][nt] = __builtin_amdgcn_mfma_f32_16x16x32_bf16(al, bxh[nt], acc[g][nt], 0,0,0);
        }
      }
    }
    // ---- pass 2: Whh . h^T (bf16x3), skip at t=0 ----
    if (t > 0) {
#pragma unroll
      for (int kt=0; kt<4; ++kt) {
        const int bo = kt*32 + lq*8;
        bf16x8 bhh_[4], bhl_[4];
#pragma unroll
        for (int nt=0; nt<4; ++nt) {
          bhh_[nt] = *(const bf16x8*)(hhi + (nt*16+ln16)*136 + bo);
          bhl_[nt] = *(const bf16x8*)(hlo + (nt*16+ln16)*136 + bo);
        }
#pragma unroll
        for (int g=0; g<4; ++g) {
          const int co = (g*128 + w*16 + ln16)*128 + kt*32 + lq*8;
          bf16x8 ah = *(const bf16x8*)(WHhi + co);
          bf16x8 al = *(const bf16x8*)(WHlo + co);
#pragma unroll
          for (int nt=0; nt<4; ++nt) {
            acc[g][nt] = __builtin_amdgcn_mfma_f32_16x16x32_bf16(ah, bhh_[nt], acc[g][nt], 0,0,0);
            acc[g][nt] = __builtin_amdgcn_mfma_f32_16x16x32_bf16(ah, bhl_[nt], acc[g][nt], 0,0,0);
            acc[g][nt] = __builtin_amdgcn_mfma_f32_16x16x32_bf16(al, bhh_[nt], acc[g][nt], 0,0,0);
          }
        }
      }
    }
    __syncthreads();   // all x/h reads done (WAR before overwrites)

    // ---- activations + cell update (lane-local across gates) ----
#pragma unroll
    for (int nt=0; nt<4; ++nt) {
      float hv[4];
#pragma unroll
      for (int e=0; e<4; ++e) {
        float ig = fsig(acc[0][nt][e]);
        float fg = fsig(acc[1][nt][e]);
        float gg = ftanh(acc[2][nt][e]);
        float og = fsig(acc[3][nt][e]);
        float cc = fg*cst[nt][e] + ig*gg;
        cst[nt][e] = cc;
        hv[e] = og*ftanh(cc);
      }
      const int node = nt*16 + ln16;
      if (t < 15) {
        bf16x4 sh, sl;
#pragma unroll
        for (int e=0; e<4; ++e) { short h_,l_; bsplit(hv[e],h_,l_); sh[e]=h_; sl[e]=l_; }
        *(bf16x4*)(hhi + node*136 + cc0) = sh;
        *(bf16x4*)(hlo + node*136 + cc0) = sl;
      } else {
        *(float4*)(hL + (size_t)((dir?NN:0) + nb + node)*128 + cc0) =
            make_float4(hv[0], hv[1], hv[2], hv[3]);
      }
    }
  }
}

// ---------------- GGC scatter-add: a[dst] += m[src] (128 floats/edge) ----------------
__global__ void scatter_add_kernel(float* __restrict__ a, const float* __restrict__ m,
                                   const int* __restrict__ src, const int* __restrict__ dst) {
  int wid = (blockIdx.x*256 + threadIdx.x) >> 6;
  int lane = threadIdx.x & 63;
  int s = src[wid], d = dst[wid];
  const float* mr = m + (size_t)s*128;
  float* ar = a + (size_t)d*128;
  atomicAdd(ar + lane, mr[lane]);
  atomicAdd(ar + 64 + lane, mr[64 + lane]);
}

// ---------------- GRU pointwise ----------------
__global__ void gru_update_kernel(float* __restrict__ hh, const float* __restrict__ gi,
                                  const float* __restrict__ gh) {
  int idx = blockIdx.x*256 + threadIdx.x;
  int n = idx >> 7, j = idx & 127;
  const float* gin = gi + (size_t)n*384;
  const float* ghn = gh + (size_t)n*384;
  float r  = fsig(gin[j] + ghn[j]);
  float z  = fsig(gin[128+j] + ghn[128+j]);
  float nn2 = ftanh(gin[256+j] + r*ghn[256+j]);
  float h = hh[idx];
  hh[idx] = (1.0f - z)*nn2 + z*h;
}

// ---------------- LayerNorm (+optional residual add) + leaky relu ----------------
__global__ void ln_lrelu_kernel(float* __restrict__ out, const float* __restrict__ x,
                                const float* __restrict__ add,
                                const float* __restrict__ g, const float* __restrict__ b) {
  int n = blockIdx.x, j = threadIdx.x;   // 128 threads
  size_t base = (size_t)n*128;
  float v = x[base+j];
  if (add) v += add[base+j];
  __shared__ float sh[4];
  float s = v;
#pragma unroll
  for (int m=32; m>=1; m>>=1) s += __shfl_xor(s, m, 64);
  if ((j&63)==0) sh[j>>6] = s;
  __syncthreads();
  float mean = (sh[0]+sh[1]) * 0.0078125f;
  float d = v - mean;
  float q = d*d;
#pragma unroll
  for (int m=32; m>=1; m>>=1) q += __shfl_xor(q, m, 64);
  if ((j&63)==0) sh[2+(j>>6)] = q;
  __syncthreads();
  float var = (sh[2]+sh[3]) * 0.0078125f;
  float y = d * rsqrtf(var + 1e-5f) * g[j] + b[j];
  out[base+j] = (y >= 0.0f) ? y : 0.01f*y;
}

// ---------------- segment mean (contiguous 128-node segments) ----------------
__global__ void segmean_kernel(float* __restrict__ out, const float* __restrict__ x,
                               const float* __restrict__ y) {
  int b = blockIdx.x, j = threadIdx.x;   // 128 threads, 256 blocks
  float s = 0.0f;
  for (int r=0; r<128; ++r) {
    size_t n = (size_t)(b*128 + r)*128 + j;
    s += x[n];
    if (y) s += y[n];
  }
  out[(size_t)b*128 + j] = s * 0.0078125f;
}

// ---------------- classifier head ----------------
__global__ void cls_kernel(float* __restrict__ out, const float* __restrict__ h2,
                           const float* __restrict__ Wc, const float* __restrict__ bc) {
  int gid = blockIdx.x*256 + threadIdx.x;
  if (gid >= BB*10) return;
  int mrow = gid/10, c = gid - mrow*10;
  const float* arow = h2 + (size_t)mrow*128;
  const float* wrow = Wc + (size_t)c*128;
  float s = bc[c];
  for (int k=0;k<128;++k) s += arow[k]*wrow[k];
  out[gid] = s;
}

__global__ void bail_kernel(float* out, float v) {
  if (threadIdx.x==0 && blockIdx.x==0) out[0] = v;
}

// ---------------- host orchestration ----------------
extern "C" void kernel_launch(void* const* d_in, const int* in_sizes, int n_in,
                              void* d_out, int out_size, void* d_ws, size_t ws_size,
                              hipStream_t stream)
{
  const int* act_ids  = (const int*)d_in[0];
  const int* dur_ids  = (const int*)d_in[1];
  const int* act2_ids = (const int*)d_in[2];
  const int* nbr_a2d  = (const int*)d_in[3];
  const int* nbr_d2a  = (const int*)d_in[4];
  const int* src2     = (const int*)d_in[5];
  const int* dst2     = (const int*)d_in[6];
  const float* emb_act     = (const float*)d_in[8];
  const float* emb_dur     = (const float*)d_in[9];
  const float* emb_act2    = (const float*)d_in[10];
  const float* transform_W = (const float*)d_in[11];
  const float* transform_b = (const float*)d_in[12];
  const float* ggc_W   = (const float*)d_in[13];
  const float* ggc_b   = (const float*)d_in[14];
  const float* gru_Wih = (const float*)d_in[15];
  const float* gru_Whh = (const float*)d_in[16];
  const float* gru_bih = (const float*)d_in[17];
  const float* gru_bhh = (const float*)d_in[18];
  const float* hn_g    = (const float*)d_in[19];
  const float* hn_b    = (const float*)d_in[20];
  const float* lstm_Wih = (const float*)d_in[21];
  const float* lstm_Whh = (const float*)d_in[22];
  const float* lstm_bih = (const float*)d_in[23];
  const float* lstm_bhh = (const float*)d_in[24];
  const float* fcs_W = (const float*)d_in[25];
  const float* fcs_b = (const float*)d_in[26];
  const float* fcn_W = (const float*)d_in[27];
  const float* fcn_b = (const float*)d_in[28];
  const float* n1_g = (const float*)d_in[29];
  const float* n1_b = (const float*)d_in[30];
  const float* n3_g = (const float*)d_in[31];
  const float* n3_b = (const float*)d_in[32];
  const float* mh_W1 = (const float*)d_in[33];
  const float* mh_b1 = (const float*)d_in[34];
  const float* mh_W2 = (const float*)d_in[35];
  const float* mh_b2 = (const float*)d_in[36];
  const float* mo_W1 = (const float*)d_in[37];
  const float* mo_b1 = (const float*)d_in[38];
  const float* mo_W2 = (const float*)d_in[39];
  const float* mo_b2 = (const float*)d_in[40];
  const float* mlp_W1 = (const float*)d_in[41];
  const float* mlp_b1 = (const float*)d_in[42];
  const float* mlp_W2 = (const float*)d_in[43];
  const float* mlp_b2 = (const float*)d_in[44];
  const float* cls_W = (const float*)d_in[45];
  const float* cls_b = (const float*)d_in[46];

  float* ws = (float*)d_ws;
  float* ha   = ws;
  float* hd   = ws + (size_t)NF;
  float* hg2  = ws + 2*(size_t)NF;
  float* res  = ws + 3*(size_t)NF;
  float* hh   = ws + 4*(size_t)NF;
  float* SCR  = ws + 5*(size_t)NF;
  float* mb   = SCR;
  float* abuf = SCR + (size_t)NF;
  float* gi   = SCR + 2*(size_t)NF;
  float* gh   = SCR + 5*(size_t)NF;
  float* hnf  = mb;
  float* hLb  = SCR + 8*(size_t)NF;
  float* SMALL = ws + 15*(size_t)NF;
  float* hg2m = SMALL;
  float* hgm  = SMALL + 32768;
  float* o1b  = SMALL + 65536;
  float* o2b  = SMALL + 98304;
  float* t1b  = SMALL + 131072;
  float* t2b  = SMALL + 163840;
  float* h1b  = SMALL + 196608;
  float* h2b  = SMALL + 262144;
  float* bsum = SMALL + 294912;
  float* WTb  = SMALL + 296960;
  const size_t NEED_BYTES = (size_t)(15*(size_t)NF + 296960 + 1032192) * 4;
  if (ws_size < NEED_BYTES) {
    hipMemsetAsync(d_out, 0, (size_t)out_size*sizeof(float), stream);
    bail_kernel<<<1,64,0,stream>>>((float*)d_out, (float)ws_size);
    return;
  }
  float* na = hg2;
  float* nd = res;

  const int O_TRANSFORM = 0;
  const int O_GGC      = 32768;
  const int O_GRUWIH   = 49152;
  const int O_GRUWHH   = 98304;
  const int O_SPLIT    = 147456;   // bf16 split arena: 16 x 65536 shorts = 524288 floats
  const int O_FCS      = 671744;
  const int O_FCN      = 737280;
  const int O_MH1      = 802816;
  const int O_MH2      = 819200;
  const int O_MO1      = 835584;
  const int O_MO2      = 851968;
  const int O_MLP1     = 868352;
  const int O_MLP2     = 999424;

  // split-weight arena (shorts): [WIhi x4 | WIlo x4 | WHhi x4 | WHlo x4]
  short* SPL = (short*)(WTb + O_SPLIT);
  short* WIhi = SPL;
  short* WIlo = SPL + 4*65536;
  short* WHhi = SPL + 8*65536;
  short* WHlo = SPL + 12*65536;

  TDescArr da;
  int di = 0;
  auto addT = [&](const float* s, float* d, int R, int C){ da.d[di].src=s; da.d[di].dst=d; da.d[di].R=R; da.d[di].C=C; ++di; };
  addT(transform_W, WTb + O_TRANSFORM, 128, 256);
  addT(ggc_W,   WTb + O_GGC,    128, 128);
  addT(gru_Wih, WTb + O_GRUWIH, 384, 128);
  addT(gru_Whh, WTb + O_GRUWHH, 384, 128);
  for (int i=0;i<4;++i) addT(fcs_W + (size_t)i*16384, WTb + O_FCS + i*16384, 128, 128);
  for (int i=0;i<4;++i) addT(fcn_W + (size_t)i*16384, WTb + O_FCN + i*16384, 128, 128);
  addT(mh_W1, WTb + O_MH1, 128, 128);
  addT(mh_W2, WTb + O_MH2, 128, 128);
  addT(mo_W1, WTb + O_MO1, 128, 128);
  addT(mo_W2, WTb + O_MO2, 128, 128);
  addT(mlp_W1, WTb + O_MLP1, 256, 512);
  addT(mlp_W2, WTb + O_MLP2, 128, 256);
  transpose_many<<<dim3(512, di), 256, 0, stream>>>(da);
  bias_sum_kernel<<<8, 256, 0, stream>>>(lstm_bih, lstm_bhh, bsum);
  wsplit_kernel<<<(4*512*128)/256, 256, 0, stream>>>(lstm_Wih, WIhi, WIlo);
  wsplit_kernel<<<(4*512*128)/256, 256, 0, stream>>>(lstm_Whh, WHhi, WHlo);

  auto smemK = [](int K, int BN){ return (size_t)(32*(K+4) + 16*BN)*4; };
  const int gN = NN/32;
  const int gB = BB/32;

  embed3_kernel<<<dim3(NF/256, 3), 256, 0, stream>>>(act_ids, dur_ids, act2_ids,
      emb_act, emb_dur, emb_act2, ha, hd, hg2);
  gemm_nt<128,0><<<gN, 256, smemK(256,128), stream>>>(hg2, hd, nullptr, nullptr, 128,
      WTb + O_TRANSFORM, transform_b, res, 256, 0);
  hipMemcpyAsync(hh, res, (size_t)NF*4, hipMemcpyDeviceToDevice, stream);

  for (int it=0; it<2; ++it) {
    gemm_nt<128,0><<<gN, 256, smemK(128,128), stream>>>(hh, nullptr, nullptr, nullptr, 128,
        WTb + O_GGC, ggc_b, mb, 128, 0);
    hipMemsetAsync(abuf, 0, (size_t)NF*4, stream);
    scatter_add_kernel<<<E2N/4, 256, 0, stream>>>(abuf, mb, src2, dst2);
    gemm_nt<384,0><<<gN, 256, smemK(128,384), stream>>>(abuf, nullptr, nullptr, nullptr, 128,
        WTb + O_GRUWIH, gru_bih, gi, 128, 0);
    gemm_nt<384,0><<<gN, 256, smemK(128,384), stream>>>(hh, nullptr, nullptr, nullptr, 128,
        WTb + O_GRUWHH, gru_bhh, gh, 128, 0);
    gru_update_kernel<<<NF/256, 256, 0, stream>>>(hh, gi, gh);
  }
  ln_lrelu_kernel<<<NN, 128, 0, stream>>>(hnf, hh, res, hn_g, hn_b);
  segmean_kernel<<<BB, 128, 0, stream>>>(hg2m, hnf, nullptr);

  for (int l=0; l<2; ++l) {
    const int i0 = l*2 + 0, i1 = l*2 + 1;
    lstm_fused_kernel<<<(2*NN)/64, 512, 69632, stream>>>(hLb, ha, hd, nbr_a2d, nbr_d2a,
        WIhi + i0*65536, WIlo + i0*65536, WHhi + i0*65536, WHlo + i0*65536,
        WIhi + i1*65536, WIlo + i1*65536, WHhi + i1*65536, WHlo + i1*65536,
        bsum + i0*512, bsum + i1*512);
    gemm_nt<128,0><<<gN, 256, smemK(128,128), stream>>>(hd, nullptr, nullptr, nullptr, 128,
        WTb + O_FCS + i0*16384, fcs_b + i0*128, nd, 128, 0);
    gemm_nt<128,0><<<gN, 256, smemK(128,128), stream>>>(hLb, nullptr, nullptr, nullptr, 128,
        WTb + O_FCN + i0*16384, fcn_b + i0*128, nd, 128, 1);
    gemm_nt<128,0><<<gN, 256, smemK(128,128), stream>>>(ha, nullptr, nullptr, nullptr, 128,
        WTb + O_FCS + i1*16384, fcs_b + i1*128, na, 128, 0);
    gemm_nt<128,0><<<gN, 256, smemK(128,128), stream>>>(hLb + (size_t)NN*128, nullptr, nullptr, nullptr, 128,
        WTb + O_FCN + i1*16384, fcn_b + i1*128, na, 128, 1);
    ln_lrelu_kernel<<<NN, 128, 0, stream>>>(na, na, nullptr, n1_g + i0*128, n1_b + i0*128);
    ln_lrelu_kernel<<<NN, 128, 0, stream>>>(nd, nd, nullptr, n1_g + i1*128, n1_b + i1*128);
    ln_lrelu_kernel<<<NN, 128, 0, stream>>>(ha, ha, na, n3_g + i0*128, n3_b + i0*128);
    ln_lrelu_kernel<<<NN, 128, 0, stream>>>(hd, hd, nd, n3_g + i1*128, n3_b + i1*128);
  }
  segmean_kernel<<<BB, 128, 0, stream>>>(hgm, ha, hd);

  gemm_nt<128,1><<<gB, 256, smemK(128,128), stream>>>(hg2m, nullptr, nullptr, nullptr, 128,
      WTb + O_MO1, mo_b1, t1b, 128, 0);
  gemm_nt<128,1><<<gB, 256, smemK(128,128), stream>>>(t1b, nullptr, nullptr, nullptr, 128,
      WTb + O_MO2, mo_b2, o1b, 128, 0);
  gemm_nt<128,1><<<gB, 256, smemK(128,128), stream>>>(hgm, nullptr, nullptr, nullptr, 128,
      WTb + O_MH1, mh_b1, t2b, 128, 0);
  gemm_nt<128,1><<<gB, 256, smemK(128,128), stream>>>(t2b, nullptr, nullptr, nullptr, 128,
      WTb + O_MH2, mh_b2, o2b, 128, 0);
  gemm_nt<256,0><<<gB, 256, smemK(256,256), stream>>>(o1b, hg2m, nullptr, nullptr, 128,
      WTb + O_MLP1, nullptr, h1b, 256, 0);
  gemm_nt<256,1><<<gB, 256, smemK(256,256), stream>>>(o2b, hgm, nullptr, nullptr, 128,
      WTb + O_MLP1 + 256*256, mlp_b1, h1b, 256, 1);
  gemm_nt<128,1><<<gB, 256, smemK(256,128), stream>>>(h1b, h1b + 128, nullptr, nullptr, 256,
      WTb + O_MLP2, mlp_b2, h2b, 256, 0);
  cls_kernel<<<10, 256, 0, stream>>>((float*)d_out, h2b, cls_W, cls_b);
}

// Round 6
// 4276.546 us; speedup vs baseline: 1.3321x; 1.0556x over previous
//
#include <hip/hip_runtime.h>
#include <math.h>

#define NN 32768
#define HH 128
#define DD 16
#define BB 256
#define E2N (NN*DD)
#define NF (NN*HH)

typedef __attribute__((ext_vector_type(8))) short bf16x8;
typedef __attribute__((ext_vector_type(4))) short bf16x4;
typedef __attribute__((ext_vector_type(4))) float f32x4;

__device__ __forceinline__ float fsig(float x) { return 1.0f/(1.0f + __expf(-x)); }
__device__ __forceinline__ float ftanh(float x) {
  float cx = fminf(fmaxf(x, -15.0f), 15.0f);
  float e = __expf(2.0f*cx);
  return 1.0f - 2.0f/(e + 1.0f);
}

// round-to-nearest-even fp32 -> bf16 (top 16 bits)
__device__ __forceinline__ unsigned bf16_rne(float x) {
  unsigned u = __float_as_uint(x);
  return (u + 0x7FFFu + ((u >> 16) & 1u)) >> 16;
}
__device__ __forceinline__ void bsplit(float x, short& hi, short& lo) {
  unsigned hb = bf16_rne(x);
  float hf = __uint_as_float(hb << 16);
  hi = (short)hb;
  lo = (short)bf16_rne(x - hf);
}

// ---------------- transpose prep (weights -> [K][Nout] layout) ----------------
struct TDesc { const float* src; float* dst; int R; int C; };
struct TDescArr { TDesc d[26]; };

__global__ void transpose_many(TDescArr da) {
  TDesc t = da.d[blockIdx.y];
  int idx = blockIdx.x*256 + threadIdx.x;
  if (idx < t.R*t.C) {
    int r = idx / t.C, c = idx - r*t.C;
    t.dst[(size_t)c*t.R + r] = t.src[idx];
  }
}

__global__ void bias_sum_kernel(const float* __restrict__ bih, const float* __restrict__ bhh,
                                float* __restrict__ bsum) {
  int i = blockIdx.x*256 + threadIdx.x;
  if (i < 2048) bsum[i] = bih[i] + bhh[i];
}

// split 4 matrices [512][128] fp32 -> bf16 hi/lo (same layout)
__global__ void wsplit_kernel(const float* __restrict__ W,
                              short* __restrict__ hi, short* __restrict__ lo) {
  int i = blockIdx.x*256 + threadIdx.x;   // 4*512*128 elems
  short h, l;
  bsplit(W[i], h, l);
  hi[i] = h; lo[i] = l;
}

// ---------------- embeddings ----------------
__global__ void embed3_kernel(const int* __restrict__ a_ids, const int* __restrict__ d_ids,
                              const int* __restrict__ a2_ids,
                              const float* __restrict__ ea, const float* __restrict__ ed,
                              const float* __restrict__ ea2,
                              float* __restrict__ ha, float* __restrict__ hd,
                              float* __restrict__ hg2) {
  int idx = blockIdx.x*256 + threadIdx.x;
  int n = idx >> 7, j = idx & 127;
  int w = blockIdx.y;
  if (w == 0)      ha[idx]  = ea[(size_t)a_ids[n]*128 + j];
  else if (w == 1) hd[idx]  = ed[(size_t)d_ids[n]*128 + j];
  else             hg2[idx] = ea2[(size_t)a2_ids[n]*128 + j];
}

// ---------------- generic GEMM: C = act(A @ W^T + bias + beta*C) ----------------
template<int BN, int ACT>
__global__ __launch_bounds__(256) void gemm_nt(
    const float* __restrict__ A0, const float* __restrict__ A1,
    const float* __restrict__ A2, const float* __restrict__ A3,
    int lda, const float* __restrict__ WT, const float* __restrict__ bias,
    float* __restrict__ C, int K, int beta)
{
  extern __shared__ float sm[];
  const int KP = K + 4;
  float* At = sm;             // [32][KP]
  float* Bc = sm + 32*KP;     // [16][BN]
  const int tid = threadIdx.x;
  const int m0 = blockIdx.x*32;
  const int ng = tid >> 5, cg = tid & 31;
  const int n0 = ng*4, c4 = cg*4;
  constexpr int G = BN/128;
  float acc[G][4][4];
#pragma unroll
  for (int g=0; g<G; ++g)
#pragma unroll
    for (int i=0;i<4;++i)
#pragma unroll
      for (int e=0;e<4;++e) acc[g][i][e] = 0.0f;

  const int nf4 = K >> 2;
  for (int idx = tid; idx < 32*nf4; idx += 256) {
    int row = idx / nf4;
    int kk = (idx - row*nf4) << 2;
    const float* Ap = (kk < 128) ? A0 : (kk < 256) ? A1 : (kk < 384) ? A2 : A3;
    float4 v = *(const float4*)(Ap + (size_t)(m0+row)*lda + (kk & 127));
    *(float4*)(At + row*KP + kk) = v;
  }
  const int nchunk = K >> 4;
  for (int kc = 0; kc < nchunk; ++kc) {
    __syncthreads();
    for (int idx = tid; idx < 16*(BN/4); idx += 256) {
      int kk = idx / (BN/4);
      int jq = idx - kk*(BN/4);
      *(float4*)(Bc + kk*BN + jq*4) = *(const float4*)(WT + (size_t)(kc*16+kk)*BN + jq*4);
    }
    __syncthreads();
    for (int k=0;k<16;++k) {
      const int kk = kc*16 + k;
      float av[4];
#pragma unroll
      for (int i=0;i<4;++i) av[i] = At[(n0+i)*KP + kk];
#pragma unroll
      for (int g=0; g<G; ++g) {
        float4 bv = *(const float4*)(Bc + k*BN + g*128 + c4);
        float bb[4] = {bv.x, bv.y, bv.z, bv.w};
#pragma unroll
        for (int i=0;i<4;++i)
#pragma unroll
          for (int e=0;e<4;++e)
            acc[g][i][e] += av[i]*bb[e];
      }
    }
  }
#pragma unroll
  for (int g=0; g<G; ++g) {
#pragma unroll
    for (int i=0;i<4;++i) {
      float* dst = C + (size_t)(m0+n0+i)*BN + g*128 + c4;
      float o[4];
#pragma unroll
      for (int e=0;e<4;++e) o[e] = acc[g][i][e];
      if (bias) {
#pragma unroll
        for (int e=0;e<4;++e) o[e] += bias[g*128 + c4 + e];
      }
      if (beta) {
        float4 p = *(const float4*)dst;
        o[0]+=p.x; o[1]+=p.y; o[2]+=p.z; o[3]+=p.w;
      }
      if (ACT==1) {
#pragma unroll
        for (int e=0;e<4;++e) o[e] = fmaxf(o[e], 0.0f);
      }
      *(float4*)dst = make_float4(o[0],o[1],o[2],o[3]);
    }
  }
}

// ---------------- fused MFMA LSTM aggregator v2 ----------------
// 64 nodes/block, 8 waves. All weight A-fragments (WI/WH hi/lo) preloaded into
// ~256 VGPRs (loop-invariant; LDS caps occupancy at 4 waves/SIMD so <=~450
// regs is free). Gather for step t+1 prefetched into registers during step t's
// MFMA block (T14 async-stage) — gather latency off the critical path.
__global__ __launch_bounds__(512) void lstm_fused_kernel(
    float* __restrict__ hL,
    const float* __restrict__ fs0, const float* __restrict__ fs1,
    const int* __restrict__ nbrA, const int* __restrict__ nbrD,
    const short* __restrict__ WIhi0, const short* __restrict__ WIlo0,
    const short* __restrict__ WHhi0, const short* __restrict__ WHlo0,
    const short* __restrict__ WIhi1, const short* __restrict__ WIlo1,
    const short* __restrict__ WHhi1, const short* __restrict__ WHlo1,
    const float* __restrict__ bsum0, const float* __restrict__ bsum1)
{
  extern __shared__ short smem[];
  short* xhi = smem;            // [64][136]
  short* xlo = smem + 8704;
  short* hhi = smem + 17408;
  short* hlo = smem + 26112;
  const int tid = threadIdx.x;
  const int w = tid >> 6;          // wave 0..7
  const int lane = tid & 63;
  const int ln16 = lane & 15;
  const int lq = lane >> 4;        // 0..3
  const int b = blockIdx.x;
  const bool dir = (b >= 512);
  const int nb = (dir ? (b - 512) : b) * 64;
  const int* nbr = dir ? nbrD : nbrA;
  const float* fs = dir ? fs1 : fs0;
  const short* WIhi = dir ? WIhi1 : WIhi0;
  const short* WIlo = dir ? WIlo1 : WIlo0;
  const short* WHhi = dir ? WHhi1 : WHhi0;
  const short* WHlo = dir ? WHlo1 : WHlo0;
  const float* bsum = dir ? bsum1 : bsum0;

  // ---- loop-invariant weight fragments -> registers (static indexing only) ----
  bf16x8 wIh[4][4], wIl[4][4], wHh[4][4], wHl[4][4];   // [kt][g]
#pragma unroll
  for (int kt=0; kt<4; ++kt)
#pragma unroll
    for (int g=0; g<4; ++g) {
      const int co = (g*128 + w*16 + ln16)*128 + kt*32 + lq*8;
      wIh[kt][g] = *(const bf16x8*)(WIhi + co);
      wIl[kt][g] = *(const bf16x8*)(WIlo + co);
      wHh[kt][g] = *(const bf16x8*)(WHhi + co);
      wHl[kt][g] = *(const bf16x8*)(WHlo + co);
    }

  f32x4 bias[4];
#pragma unroll
  for (int g=0; g<4; ++g)
    bias[g] = *(const f32x4*)(bsum + g*128 + w*16 + lq*4);

  f32x4 acc[4][4];   // [gate][nt]
  f32x4 cst[4];      // [nt]
#pragma unroll
  for (int nt=0; nt<4; ++nt)
#pragma unroll
    for (int e=0; e<4; ++e) cst[nt][e] = 0.0f;

  const int gr_r = tid >> 3;        // gather row 0..63
  const int gcf  = (tid & 7) * 16;  // float col 0..112
  const int cc0  = w*16 + lq*4;     // this lane's h-col base
  const int* nbr_row = nbr + (size_t)(nb + gr_r)*DD;

  // prologue: gather step-0 rows into registers
  float4 gv0, gv1, gv2, gv3;
  {
    const float* src = fs + (size_t)nbr_row[0]*128 + gcf;
    gv0 = *(const float4*)(src);
    gv1 = *(const float4*)(src + 4);
    gv2 = *(const float4*)(src + 8);
    gv3 = *(const float4*)(src + 12);
  }

#pragma unroll 1
  for (int t=0; t<16; ++t) {
    int idx_next = (t < 15) ? nbr_row[t+1] : 0;   // issue index load early
    // ---- write x(t) from prefetched regs: bsplit -> LDS ----
    {
      short* dh = xhi + gr_r*136 + gcf;
      short* dl = xlo + gr_r*136 + gcf;
      float vs[16];
      vs[0]=gv0.x; vs[1]=gv0.y; vs[2]=gv0.z; vs[3]=gv0.w;
      vs[4]=gv1.x; vs[5]=gv1.y; vs[6]=gv1.z; vs[7]=gv1.w;
      vs[8]=gv2.x; vs[9]=gv2.y; vs[10]=gv2.z; vs[11]=gv2.w;
      vs[12]=gv3.x; vs[13]=gv3.y; vs[14]=gv3.z; vs[15]=gv3.w;
#pragma unroll
      for (int q=0; q<4; ++q) {
        bf16x4 sh, sl;
#pragma unroll
        for (int e=0; e<4; ++e) { short h_,l_; bsplit(vs[q*4+e],h_,l_); sh[e]=h_; sl[e]=l_; }
        *(bf16x4*)(dh + q*4) = sh;
        *(bf16x4*)(dl + q*4) = sl;
      }
    }
    // ---- init acc with (bih+bhh) ----
#pragma unroll
    for (int g=0; g<4; ++g)
#pragma unroll
      for (int nt=0; nt<4; ++nt)
        acc[g][nt] = bias[g];
    __syncthreads();   // x(t) tile + h(t-1) writes visible

    // ---- pass 1: Wih . x^T (bf16x3, weights in regs) ----
#pragma unroll
    for (int kt=0; kt<4; ++kt) {
      const int bo = kt*32 + lq*8;
      bf16x8 bxh[4], bxl[4];
#pragma unroll
      for (int nt=0; nt<4; ++nt) {
        bxh[nt] = *(const bf16x8*)(xhi + (nt*16+ln16)*136 + bo);
        bxl[nt] = *(const bf16x8*)(xlo + (nt*16+ln16)*136 + bo);
      }
#pragma unroll
      for (int g=0; g<4; ++g) {
#pragma unroll
        for (int nt=0; nt<4; ++nt) {
          acc[g][nt] = __builtin_amdgcn_mfma_f32_16x16x32_bf16(wIh[kt][g], bxh[nt], acc[g][nt], 0,0,0);
          acc[g][nt] = __builtin_amdgcn_mfma_f32_16x16x32_bf16(wIh[kt][g], bxl[nt], acc[g][nt], 0,0,0);
          acc[g][nt] = __builtin_amdgcn_mfma_f32_16x16x32_bf16(wIl[kt][g], bxh[nt], acc[g][nt], 0,0,0);
        }
      }
    }
    // ---- issue gather for t+1 (hidden under pass 2) ----
    if (t < 15) {
      const float* src = fs + (size_t)idx_next*128 + gcf;
      gv0 = *(const float4*)(src);
      gv1 = *(const float4*)(src + 4);
      gv2 = *(const float4*)(src + 8);
      gv3 = *(const float4*)(src + 12);
    }
    // ---- pass 2: Whh . h^T (bf16x3), skip at t=0 ----
    if (t > 0) {
#pragma unroll
      for (int kt=0; kt<4; ++kt) {
        const int bo = kt*32 + lq*8;
        bf16x8 bhh_[4], bhl_[4];
#pragma unroll
        for (int nt=0; nt<4; ++nt) {
          bhh_[nt] = *(const bf16x8*)(hhi + (nt*16+ln16)*136 + bo);
          bhl_[nt] = *(const bf16x8*)(hlo + (nt*16+ln16)*136 + bo);
        }
#pragma unroll
        for (int g=0; g<4; ++g) {
#pragma unroll
          for (int nt=0; nt<4; ++nt) {
            acc[g][nt] = __builtin_amdgcn_mfma_f32_16x16x32_bf16(wHh[kt][g], bhh_[nt], acc[g][nt], 0,0,0);
            acc[g][nt] = __builtin_amdgcn_mfma_f32_16x16x32_bf16(wHh[kt][g], bhl_[nt], acc[g][nt], 0,0,0);
            acc[g][nt] = __builtin_amdgcn_mfma_f32_16x16x32_bf16(wHl[kt][g], bhh_[nt], acc[g][nt], 0,0,0);
          }
        }
      }
    }
    __syncthreads();   // all x/h reads done (WAR before overwrites)

    // ---- activations + cell update (lane-local across gates) ----
#pragma unroll
    for (int nt=0; nt<4; ++nt) {
      float hv[4];
#pragma unroll
      for (int e=0; e<4; ++e) {
        float ig = fsig(acc[0][nt][e]);
        float fg = fsig(acc[1][nt][e]);
        float gg = ftanh(acc[2][nt][e]);
        float og = fsig(acc[3][nt][e]);
        float cc = fg*cst[nt][e] + ig*gg;
        cst[nt][e] = cc;
        hv[e] = og*ftanh(cc);
      }
      const int node = nt*16 + ln16;
      if (t < 15) {
        bf16x4 sh, sl;
#pragma unroll
        for (int e=0; e<4; ++e) { short h_,l_; bsplit(hv[e],h_,l_); sh[e]=h_; sl[e]=l_; }
        *(bf16x4*)(hhi + node*136 + cc0) = sh;
        *(bf16x4*)(hlo + node*136 + cc0) = sl;
      } else {
        *(float4*)(hL + (size_t)((dir?NN:0) + nb + node)*128 + cc0) =
            make_float4(hv[0], hv[1], hv[2], hv[3]);
      }
    }
  }
}

// ---------------- GGC scatter-add: a[dst] += m[src] (128 floats/edge) ----------------
__global__ void scatter_add_kernel(float* __restrict__ a, const float* __restrict__ m,
                                   const int* __restrict__ src, const int* __restrict__ dst) {
  int wid = (blockIdx.x*256 + threadIdx.x) >> 6;
  int lane = threadIdx.x & 63;
  int s = src[wid], d = dst[wid];
  const float* mr = m + (size_t)s*128;
  float* ar = a + (size_t)d*128;
  atomicAdd(ar + lane, mr[lane]);
  atomicAdd(ar + 64 + lane, mr[64 + lane]);
}

// ---------------- GRU pointwise ----------------
__global__ void gru_update_kernel(float* __restrict__ hh, const float* __restrict__ gi,
                                  const float* __restrict__ gh) {
  int idx = blockIdx.x*256 + threadIdx.x;
  int n = idx >> 7, j = idx & 127;
  const float* gin = gi + (size_t)n*384;
  const float* ghn = gh + (size_t)n*384;
  float r  = fsig(gin[j] + ghn[j]);
  float z  = fsig(gin[128+j] + ghn[128+j]);
  float nn2 = ftanh(gin[256+j] + r*ghn[256+j]);
  float h = hh[idx];
  hh[idx] = (1.0f - z)*nn2 + z*h;
}

// ---------------- LayerNorm (+optional residual add) + leaky relu ----------------
__global__ void ln_lrelu_kernel(float* __restrict__ out, const float* __restrict__ x,
                                const float* __restrict__ add,
                                const float* __restrict__ g, const float* __restrict__ b) {
  int n = blockIdx.x, j = threadIdx.x;   // 128 threads
  size_t base = (size_t)n*128;
  float v = x[base+j];
  if (add) v += add[base+j];
  __shared__ float sh[4];
  float s = v;
#pragma unroll
  for (int m=32; m>=1; m>>=1) s += __shfl_xor(s, m, 64);
  if ((j&63)==0) sh[j>>6] = s;
  __syncthreads();
  float mean = (sh[0]+sh[1]) * 0.0078125f;
  float d = v - mean;
  float q = d*d;
#pragma unroll
  for (int m=32; m>=1; m>>=1) q += __shfl_xor(q, m, 64);
  if ((j&63)==0) sh[2+(j>>6)] = q;
  __syncthreads();
  float var = (sh[2]+sh[3]) * 0.0078125f;
  float y = d * rsqrtf(var + 1e-5f) * g[j] + b[j];
  out[base+j] = (y >= 0.0f) ? y : 0.01f*y;
}

// ---------------- segment mean (contiguous 128-node segments) ----------------
__global__ void segmean_kernel(float* __restrict__ out, const float* __restrict__ x,
                               const float* __restrict__ y) {
  int b = blockIdx.x, j = threadIdx.x;   // 128 threads, 256 blocks
  float s = 0.0f;
  for (int r=0; r<128; ++r) {
    size_t n = (size_t)(b*128 + r)*128 + j;
    s += x[n];
    if (y) s += y[n];
  }
  out[(size_t)b*128 + j] = s * 0.0078125f;
}

// ---------------- classifier head ----------------
__global__ void cls_kernel(float* __restrict__ out, const float* __restrict__ h2,
                           const float* __restrict__ Wc, const float* __restrict__ bc) {
  int gid = blockIdx.x*256 + threadIdx.x;
  if (gid >= BB*10) return;
  int mrow = gid/10, c = gid - mrow*10;
  const float* arow = h2 + (size_t)mrow*128;
  const float* wrow = Wc + (size_t)c*128;
  float s = bc[c];
  for (int k=0;k<128;++k) s += arow[k]*wrow[k];
  out[gid] = s;
}

__global__ void bail_kernel(float* out, float v) {
  if (threadIdx.x==0 && blockIdx.x==0) out[0] = v;
}

// ---------------- host orchestration ----------------
extern "C" void kernel_launch(void* const* d_in, const int* in_sizes, int n_in,
                              void* d_out, int out_size, void* d_ws, size_t ws_size,
                              hipStream_t stream)
{
  const int* act_ids  = (const int*)d_in[0];
  const int* dur_ids  = (const int*)d_in[1];
  const int* act2_ids = (const int*)d_in[2];
  const int* nbr_a2d  = (const int*)d_in[3];
  const int* nbr_d2a  = (const int*)d_in[4];
  const int* src2     = (const int*)d_in[5];
  const int* dst2     = (const int*)d_in[6];
  const float* emb_act     = (const float*)d_in[8];
  const float* emb_dur     = (const float*)d_in[9];
  const float* emb_act2    = (const float*)d_in[10];
  const float* transform_W = (const float*)d_in[11];
  const float* transform_b = (const float*)d_in[12];
  const float* ggc_W   = (const float*)d_in[13];
  const float* ggc_b   = (const float*)d_in[14];
  const float* gru_Wih = (const float*)d_in[15];
  const float* gru_Whh = (const float*)d_in[16];
  const float* gru_bih = (const float*)d_in[17];
  const float* gru_bhh = (const float*)d_in[18];
  const float* hn_g    = (const float*)d_in[19];
  const float* hn_b    = (const float*)d_in[20];
  const float* lstm_Wih = (const float*)d_in[21];
  const float* lstm_Whh = (const float*)d_in[22];
  const float* lstm_bih = (const float*)d_in[23];
  const float* lstm_bhh = (const float*)d_in[24];
  const float* fcs_W = (const float*)d_in[25];
  const float* fcs_b = (const float*)d_in[26];
  const float* fcn_W = (const float*)d_in[27];
  const float* fcn_b = (const float*)d_in[28];
  const float* n1_g = (const float*)d_in[29];
  const float* n1_b = (const float*)d_in[30];
  const float* n3_g = (const float*)d_in[31];
  const float* n3_b = (const float*)d_in[32];
  const float* mh_W1 = (const float*)d_in[33];
  const float* mh_b1 = (const float*)d_in[34];
  const float* mh_W2 = (const float*)d_in[35];
  const float* mh_b2 = (const float*)d_in[36];
  const float* mo_W1 = (const float*)d_in[37];
  const float* mo_b1 = (const float*)d_in[38];
  const float* mo_W2 = (const float*)d_in[39];
  const float* mo_b2 = (const float*)d_in[40];
  const float* mlp_W1 = (const float*)d_in[41];
  const float* mlp_b1 = (const float*)d_in[42];
  const float* mlp_W2 = (const float*)d_in[43];
  const float* mlp_b2 = (const float*)d_in[44];
  const float* cls_W = (const float*)d_in[45];
  const float* cls_b = (const float*)d_in[46];

  float* ws = (float*)d_ws;
  float* ha   = ws;
  float* hd   = ws + (size_t)NF;
  float* hg2  = ws + 2*(size_t)NF;
  float* res  = ws + 3*(size_t)NF;
  float* hh   = ws + 4*(size_t)NF;
  float* SCR  = ws + 5*(size_t)NF;
  float* mb   = SCR;
  float* abuf = SCR + (size_t)NF;
  float* gi   = SCR + 2*(size_t)NF;
  float* gh   = SCR + 5*(size_t)NF;
  float* hnf  = mb;
  float* hLb  = SCR + 8*(size_t)NF;
  float* SMALL = ws + 15*(size_t)NF;
  float* hg2m = SMALL;
  float* hgm  = SMALL + 32768;
  float* o1b  = SMALL + 65536;
  float* o2b  = SMALL + 98304;
  float* t1b  = SMALL + 131072;
  float* t2b  = SMALL + 163840;
  float* h1b  = SMALL + 196608;
  float* h2b  = SMALL + 262144;
  float* bsum = SMALL + 294912;
  float* WTb  = SMALL + 296960;
  const size_t NEED_BYTES = (size_t)(15*(size_t)NF + 296960 + 1032192) * 4;
  if (ws_size < NEED_BYTES) {
    hipMemsetAsync(d_out, 0, (size_t)out_size*sizeof(float), stream);
    bail_kernel<<<1,64,0,stream>>>((float*)d_out, (float)ws_size);
    return;
  }
  float* na = hg2;
  float* nd = res;

  const int O_TRANSFORM = 0;
  const int O_GGC      = 32768;
  const int O_GRUWIH   = 49152;
  const int O_GRUWHH   = 98304;
  const int O_SPLIT    = 147456;   // bf16 split arena: 16 x 65536 shorts = 524288 floats
  const int O_FCS      = 671744;
  const int O_FCN      = 737280;
  const int O_MH1      = 802816;
  const int O_MH2      = 819200;
  const int O_MO1      = 835584;
  const int O_MO2      = 851968;
  const int O_MLP1     = 868352;
  const int O_MLP2     = 999424;

  short* SPL = (short*)(WTb + O_SPLIT);
  short* WIhi = SPL;
  short* WIlo = SPL + 4*65536;
  short* WHhi = SPL + 8*65536;
  short* WHlo = SPL + 12*65536;

  TDescArr da;
  int di = 0;
  auto addT = [&](const float* s, float* d, int R, int C){ da.d[di].src=s; da.d[di].dst=d; da.d[di].R=R; da.d[di].C=C; ++di; };
  addT(transform_W, WTb + O_TRANSFORM, 128, 256);
  addT(ggc_W,   WTb + O_GGC,    128, 128);
  addT(gru_Wih, WTb + O_GRUWIH, 384, 128);
  addT(gru_Whh, WTb + O_GRUWHH, 384, 128);
  for (int i=0;i<4;++i) addT(fcs_W + (size_t)i*16384, WTb + O_FCS + i*16384, 128, 128);
  for (int i=0;i<4;++i) addT(fcn_W + (size_t)i*16384, WTb + O_FCN + i*16384, 128, 128);
  addT(mh_W1, WTb + O_MH1, 128, 128);
  addT(mh_W2, WTb + O_MH2, 128, 128);
  addT(mo_W1, WTb + O_MO1, 128, 128);
  addT(mo_W2, WTb + O_MO2, 128, 128);
  addT(mlp_W1, WTb + O_MLP1, 256, 512);
  addT(mlp_W2, WTb + O_MLP2, 128, 256);
  transpose_many<<<dim3(512, di), 256, 0, stream>>>(da);
  bias_sum_kernel<<<8, 256, 0, stream>>>(lstm_bih, lstm_bhh, bsum);
  wsplit_kernel<<<(4*512*128)/256, 256, 0, stream>>>(lstm_Wih, WIhi, WIlo);
  wsplit_kernel<<<(4*512*128)/256, 256, 0, stream>>>(lstm_Whh, WHhi, WHlo);

  auto smemK = [](int K, int BN){ return (size_t)(32*(K+4) + 16*BN)*4; };
  const int gN = NN/32;
  const int gB = BB/32;

  embed3_kernel<<<dim3(NF/256, 3), 256, 0, stream>>>(act_ids, dur_ids, act2_ids,
      emb_act, emb_dur, emb_act2, ha, hd, hg2);
  gemm_nt<128,0><<<gN, 256, smemK(256,128), stream>>>(hg2, hd, nullptr, nullptr, 128,
      WTb + O_TRANSFORM, transform_b, res, 256, 0);
  hipMemcpyAsync(hh, res, (size_t)NF*4, hipMemcpyDeviceToDevice, stream);

  for (int it=0; it<2; ++it) {
    gemm_nt<128,0><<<gN, 256, smemK(128,128), stream>>>(hh, nullptr, nullptr, nullptr, 128,
        WTb + O_GGC, ggc_b, mb, 128, 0);
    hipMemsetAsync(abuf, 0, (size_t)NF*4, stream);
    scatter_add_kernel<<<E2N/4, 256, 0, stream>>>(abuf, mb, src2, dst2);
    gemm_nt<384,0><<<gN, 256, smemK(128,384), stream>>>(abuf, nullptr, nullptr, nullptr, 128,
        WTb + O_GRUWIH, gru_bih, gi, 128, 0);
    gemm_nt<384,0><<<gN, 256, smemK(128,384), stream>>>(hh, nullptr, nullptr, nullptr, 128,
        WTb + O_GRUWHH, gru_bhh, gh, 128, 0);
    gru_update_kernel<<<NF/256, 256, 0, stream>>>(hh, gi, gh);
  }
  ln_lrelu_kernel<<<NN, 128, 0, stream>>>(hnf, hh, res, hn_g, hn_b);
  segmean_kernel<<<BB, 128, 0, stream>>>(hg2m, hnf, nullptr);

  for (int l=0; l<2; ++l) {
    const int i0 = l*2 + 0, i1 = l*2 + 1;
    lstm_fused_kernel<<<(2*NN)/64, 512, 69632, stream>>>(hLb, ha, hd, nbr_a2d, nbr_d2a,
        WIhi + i0*65536, WIlo + i0*65536, WHhi + i0*65536, WHlo + i0*65536,
        WIhi + i1*65536, WIlo + i1*65536, WHhi + i1*65536, WHlo + i1*65536,
        bsum + i0*512, bsum + i1*512);
    gemm_nt<128,0><<<gN, 256, smemK(128,128), stream>>>(hd, nullptr, nullptr, nullptr, 128,
        WTb + O_FCS + i0*16384, fcs_b + i0*128, nd, 128, 0);
    gemm_nt<128,0><<<gN, 256, smemK(128,128), stream>>>(hLb, nullptr, nullptr, nullptr, 128,
        WTb + O_FCN + i0*16384, fcn_b + i0*128, nd, 128, 1);
    gemm_nt<128,0><<<gN, 256, smemK(128,128), stream>>>(ha, nullptr, nullptr, nullptr, 128,
        WTb + O_FCS + i1*16384, fcs_b + i1*128, na, 128, 0);
    gemm_nt<128,0><<<gN, 256, smemK(128,128), stream>>>(hLb + (size_t)NN*128, nullptr, nullptr, nullptr, 128,
        WTb + O_FCN + i1*16384, fcn_b + i1*128, na, 128, 1);
    ln_lrelu_kernel<<<NN, 128, 0, stream>>>(na, na, nullptr, n1_g + i0*128, n1_b + i0*128);
    ln_lrelu_kernel<<<NN, 128, 0, stream>>>(nd, nd, nullptr, n1_g + i1*128, n1_b + i1*128);
    ln_lrelu_kernel<<<NN, 128, 0, stream>>>(ha, ha, na, n3_g + i0*128, n3_b + i0*128);
    ln_lrelu_kernel<<<NN, 128, 0, stream>>>(hd, hd, nd, n3_g + i1*128, n3_b + i1*128);
  }
  segmean_kernel<<<BB, 128, 0, stream>>>(hgm, ha, hd);

  gemm_nt<128,1><<<gB, 256, smemK(128,128), stream>>>(hg2m, nullptr, nullptr, nullptr, 128,
      WTb + O_MO1, mo_b1, t1b, 128, 0);
  gemm_nt<128,1><<<gB, 256, smemK(128,128), stream>>>(t1b, nullptr, nullptr, nullptr, 128,
      WTb + O_MO2, mo_b2, o1b, 128, 0);
  gemm_nt<128,1><<<gB, 256, smemK(128,128), stream>>>(hgm, nullptr, nullptr, nullptr, 128,
      WTb + O_MH1, mh_b1, t2b, 128, 0);
  gemm_nt<128,1><<<gB, 256, smemK(128,128), stream>>>(t2b, nullptr, nullptr, nullptr, 128,
      WTb + O_MH2, mh_b2, o2b, 128, 0);
  gemm_nt<256,0><<<gB, 256, smemK(256,256), stream>>>(o1b, hg2m, nullptr, nullptr, 128,
      WTb + O_MLP1, nullptr, h1b, 256, 0);
  gemm_nt<256,1><<<gB, 256, smemK(256,256), stream>>>(o2b, hgm, nullptr, nullptr, 128,
      WTb + O_MLP1 + 256*256, mlp_b1, h1b, 256, 1);
  gemm_nt<128,1><<<gB, 256, smemK(256,128), stream>>>(h1b, h1b + 128, nullptr, nullptr, 256,
      WTb + O_MLP2, mlp_b2, h2b, 256, 0);
  cls_kernel<<<10, 256, 0, stream>>>((float*)d_out, h2b, cls_W, cls_b);
}